// Round 7
// baseline (447.999 us; speedup 1.0000x reference)
//
#include <hip/hip_runtime.h>
#include <cstdint>
#include <cstddef>

#define BN_EPS 1e-5f
#define NSLICE 128
#define BK_BITS 7
#define BK_SIZE 128
#define NBK_MAX 1024
#define EB_CAP 5120

typedef __attribute__((ext_vector_type(8))) __bf16 bf16x8;
typedef __attribute__((ext_vector_type(4))) float f32x4;
typedef __attribute__((ext_vector_type(2))) float f32x2;

// ---------------- helpers ----------------

__device__ inline uint16_t f2bf(float f){
  union {float f; uint32_t u;} v; v.f = f;
  uint32_t u = v.u;
  return (uint16_t)((u + 0x7FFFu + ((u >> 16) & 1u)) >> 16);
}

__device__ inline uint32_t pack2bf(float a, float b){
  return (uint32_t)f2bf(a) | ((uint32_t)f2bf(b) << 16);
}

__device__ inline void bf2f2(uint32_t w, float& a, float& b){
  union {uint32_t u; float f;} ua, ub;
  ua.u = w << 16; ub.u = w & 0xFFFF0000u;
  a = ua.f; b = ub.f;
}

// unpack a bf16 pair word into a packed f32x2 (low half, high half)
__device__ inline f32x2 bfpair(uint32_t w){
  union {uint32_t u; float f;} ua, ub;
  ua.u = w << 16; ub.u = w & 0xFFFF0000u;
  return (f32x2){ua.f, ub.f};
}

__device__ inline uint8_t f2fp8(float v){
  uint32_t t = (uint32_t)__builtin_amdgcn_cvt_pk_fp8_f32(v, v, 0, false);
  return (uint8_t)(t & 0xFF);
}

__device__ inline void prepW_body(const float* W, uint16_t* WTf, int K, int NOUT, int id){
  if (id >= K*NOUT) return;
  int j    = id & 7;
  int l    = (id >> 3) & 63;
  int l15  = l & 15, quad = l >> 4;
  int rest = id >> 9;
  int KS   = K >> 5;
  int ks   = rest % KS;
  int t    = rest / KS;
  int k = ks*32 + quad*8 + j;
  int n = t*16 + l15;
  WTf[id] = f2bf(W[(size_t)k*NOUT + n]);
}

// ---------------- fused init ----------------
__global__ __launch_bounds__(256) void k_misc(
    const int* __restrict__ batch, int* __restrict__ gstart, int N, int G, int cbN,
    const float* __restrict__ W1, uint16_t* __restrict__ WT1,
    const float* __restrict__ W2, uint16_t* __restrict__ WT2,
    int* __restrict__ bcur,
    float4* __restrict__ gstats4, float4* __restrict__ embsum4)
{
  int b = blockIdx.x;
  int t = threadIdx.x;
  float4 z4 = {0.f,0.f,0.f,0.f};
  if (b < 256){
    gstats4[b*256 + t] = z4;
  } else if (b < 1280){
    embsum4[(b-256)*256 + t] = z4;
  } else if (b < 1280 + cbN){
    int i = (b-1280)*256 + t;
    if (i < N){
      int bb = batch[i];
      int bp = (i > 0) ? batch[i-1] : -1;
      for (int g = bp+1; g <= bb; g++) gstart[g] = i;
      if (i == N-1){
        for (int g = bb+1; g <= G; g++) gstart[g] = N;
      }
    }
  } else if (b == 1280 + cbN){
    for (int i = t; i < NBK_MAX; i += 256) bcur[i] = i * EB_CAP;
  } else if (b < 1280 + cbN + 1 + 32){
    prepW_body(W1, WT1, 64, 128, (b - 1280 - cbN - 1)*256 + t);
  } else {
    prepW_body(W2, WT2, 128, 256, (b - 1280 - cbN - 33)*256 + t);
  }
}

// ---------------- graph preprocessing: 128-node buckets, single-phase passA ----------------
#define PA_TILE 4096

__global__ __launch_bounds__(256) void k_passA(
    const int* __restrict__ row, const int* __restrict__ col,
    int* __restrict__ bcur, uint32_t* __restrict__ ebuf, int E)
{
  __shared__ int hist[NBK_MAX];
  __shared__ int rbase[NBK_MAX];
  int t = threadIdx.x;
  int start = blockIdx.x * PA_TILE;
  for (int i = t; i < NBK_MAX; i += 256) hist[i] = 0;
  __syncthreads();
  uint32_t myv[16]; int myb[16];
  #pragma unroll
  for (int j = 0; j < 16; j++){
    int e = start + t + j*256;
    if (e < E){
      int r = row[e], c = col[e];
      myb[j] = c >> BK_BITS;
      myv[j] = ((uint32_t)r << BK_BITS) | (uint32_t)(c & (BK_SIZE-1));
      atomicAdd(&hist[myb[j]], 1);
    } else myb[j] = -1;
  }
  __syncthreads();
  for (int i = t; i < NBK_MAX; i += 256){
    int h = hist[i];
    rbase[i] = (h > 0) ? atomicAdd(&bcur[i], h) : 0;
  }
  __syncthreads();
  for (int i = t; i < NBK_MAX; i += 256) hist[i] = 0;
  __syncthreads();
  #pragma unroll
  for (int j = 0; j < 16; j++){
    if (myb[j] >= 0){
      int pos = rbase[myb[j]] + atomicAdd(&hist[myb[j]], 1);
      ebuf[pos] = myv[j];
    }
  }
}

// passB2 (128-node buckets) + inlined bucket-prefix scan + fused x->xs conversion
__global__ __launch_bounds__(256) void k_passB2(
    const uint32_t* __restrict__ ebuf, const int* __restrict__ bcur,
    int* __restrict__ offs, float* __restrict__ dinv,
    int* __restrict__ csr,
    const float4* __restrict__ x, ushort4* __restrict__ xs,
    int N, int E, int nb)
{
  __shared__ int deg[BK_SIZE];
  __shared__ int cur[BK_SIZE];
  __shared__ int ps[BK_SIZE];
  __shared__ int red[256];
  int b = blockIdx.x;
  int base = b << BK_BITS;
  int t = threadIdx.x;
  // inline scan: s = sum of counts of buckets < b
  int partial = 0;
  for (int i = t; i < NBK_MAX; i += 256){
    int cnt = bcur[i] - i*EB_CAP;
    if (i < b) partial += cnt;
  }
  red[t] = partial;
  if (t < BK_SIZE) deg[t] = 0;
  __syncthreads();
  for (int off = 128; off > 0; off >>= 1){
    if (t < off) red[t] += red[t+off];
    __syncthreads();
  }
  int s = red[0];
  int ecnt = bcur[b] - b*EB_CAP;
  const uint32_t* eb = ebuf + (size_t)b*EB_CAP;
  for (int i = t; i < ecnt; i += 256)
    atomicAdd(&deg[eb[i] & (BK_SIZE-1u)], 1);
  __syncthreads();
  int d = (t < BK_SIZE) ? deg[t] : 0;
  if (t < BK_SIZE) ps[t] = d;
  __syncthreads();
  for (int off=1; off<BK_SIZE; off<<=1){
    int x_ = 0;
    if (t < BK_SIZE && t >= off) x_ = ps[t-off];
    __syncthreads();
    if (t < BK_SIZE && t >= off) ps[t] += x_;
    __syncthreads();
  }
  if (t < BK_SIZE){
    int o = s + ps[t] - d;
    cur[t] = o;
    int n0 = base + t;
    if (n0 < N){ offs[n0] = o; dinv[n0] = 1.0f / sqrtf((float)(d + 1)); }
  }
  if (b == nb-1 && t == 0) offs[N] = E;
  __syncthreads();
  for (int i = t; i < ecnt; i += 256){
    uint32_t v = eb[i];
    int local = v & (BK_SIZE-1u);
    int pos = atomicAdd(&cur[local], 1);
    csr[pos] = (int)(v >> BK_BITS);
  }
  for (int idx = t; idx < BK_SIZE*16; idx += 256){
    int local = idx >> 4;
    int node = base + local;
    if (node < N){
      float dd = 1.0f / sqrtf((float)(deg[local] + 1));
      int c16 = idx & 15;
      float4 v = x[(size_t)node*16 + c16];
      ushort4 o;
      o.x = f2bf(v.x*dd); o.y = f2bf(v.y*dd); o.z = f2bf(v.z*dd); o.w = f2bf(v.w*dd);
      xs[(size_t)node*16 + c16] = o;
    }
  }
}

// parallel bn finalize: one block per column, slice-parallel tree reduce
__global__ __launch_bounds__(128) void k_bnfin(const float* __restrict__ region, int F, float invCount,
                        const float* __restrict__ g, const float* __restrict__ be,
                        float* __restrict__ scale, float* __restrict__ shift){
  __shared__ float ss[128], sq[128];
  int i  = blockIdx.x;
  int sl = threadIdx.x;
  ss[sl] = region[sl*2*F + i];
  sq[sl] = region[sl*2*F + F + i];
  __syncthreads();
  for (int off = 64; off > 0; off >>= 1){
    if (sl < off){ ss[sl] += ss[sl+off]; sq[sl] += sq[sl+off]; }
    __syncthreads();
  }
  if (sl == 0){
    float mu  = ss[0] * invCount;
    float var = sq[0] * invCount - mu*mu;
    if (var < 0.f) var = 0.f;
    float rstd = 1.0f / sqrtf(var + BN_EPS);
    float sc = g[i] * rstd;
    scale[i] = sc;
    shift[i] = be[i] - mu * sc;
  }
}

// ---------------- aggregation kernels ----------------
// agg1: 4 subs per node (quarter ranges x 8 lanes, 8 nodes/block) + within-
// block degree-balanced slot assignment: nodes ranked by edge count so each
// wave processes similar-length ranges (max ~= mean, kills exec-mask waste).
// Per-node accumulation order unchanged -> bit-identical per node.
// (History: cross-iteration row pipelines spill to scratch (r2/r3, 2.2x);
// nontemporal csr refetches +24MB (r5). 2-way split was +21% on agg1 (r6).)
__global__ __launch_bounds__(256) void k_agg1(
    const uint4* __restrict__ xs, const int* __restrict__ offs, const int* __restrict__ csr,
    const float* __restrict__ dinv, uint4* __restrict__ z, float* __restrict__ dsum, int N)
{
  __shared__ int s_len[8];
  __shared__ int s_ord[8];
  int tid = threadIdx.x;
  int m0 = blockIdx.x*8;
  if (tid < 8){
    int n = m0 + tid;
    s_len[tid] = (n < N) ? (offs[n+1] - offs[n]) : -1;
  }
  __syncthreads();
  if (tid < 8){
    int len = s_len[tid];
    int r = 0;
    #pragma unroll
    for (int j = 0; j < 8; j++){
      int lj = s_len[j];
      if (lj > len || (lj == len && j < tid)) r++;
    }
    s_ord[r] = tid;
  }
  __syncthreads();
  int slot    = tid >> 5;        // 0..7 (rank)
  int quarter = (tid >> 3) & 3;  // 0..3
  int lane    = tid & 7;         // 16B column
  int node = m0 + s_ord[slot];
  if (node >= N) return;
  int s0 = offs[node], e0 = offs[node+1];
  int len = e0 - s0;
  int q = len >> 2, rem = len & 3;
  int s = s0 + quarter*q + (quarter < rem ? quarter : rem);
  int e = s + q + (quarter < rem ? 1 : 0);

  f32x2 acc[4] = {};
  float ds = 0.f;
  auto add8 = [&](uint4 v){
    acc[0] += bfpair(v.x); acc[1] += bfpair(v.y);
    acc[2] += bfpair(v.z); acc[3] += bfpair(v.w);
  };
  int i = s;
  for (; i + 4 <= e; i += 4){
    int r0 = csr[i], r1 = csr[i+1], r2 = csr[i+2], r3 = csr[i+3];
    uint4 v0 = xs[r0*8 + lane];
    uint4 v1 = xs[r1*8 + lane];
    uint4 v2 = xs[r2*8 + lane];
    uint4 v3 = xs[r3*8 + lane];
    add8(v0); add8(v1); add8(v2); add8(v3);
    if (lane == 0) ds += dinv[r0] + dinv[r1] + dinv[r2] + dinv[r3];
  }
  for (; i < e; i++){
    int r0 = csr[i];
    add8(xs[r0*8 + lane]);
    if (lane == 0) ds += dinv[r0];
  }
  float d = dinv[node];
  if (quarter == 0){
    add8(xs[node*8 + lane]);           // self loop once
    if (lane == 0) ds += d;
  }
  // combine quarters: bit3 then bit4 of tid (all within the 32-lane group)
  #pragma unroll
  for (int j = 0; j < 4; j++){
    acc[j].x += __shfl_xor(acc[j].x, 8);
    acc[j].y += __shfl_xor(acc[j].y, 8);
    acc[j].x += __shfl_xor(acc[j].x, 16);
    acc[j].y += __shfl_xor(acc[j].y, 16);
  }
  ds += __shfl_xor(ds, 8);
  ds += __shfl_xor(ds, 16);
  if (quarter == 0){
    if (lane == 0) dsum[node] = ds;
    uint4 o;
    o.x = pack2bf(acc[0].x*d, acc[0].y*d);
    o.y = pack2bf(acc[1].x*d, acc[1].y*d);
    o.z = pack2bf(acc[2].x*d, acc[2].y*d);
    o.w = pack2bf(acc[3].x*d, acc[3].y*d);
    z[(node>>4)*128 + lane*16 + (node&15)] = o;
  }
}

// agg2: gather u (fp8, 16B/lane, 8 lanes/node) -> algebraic bn1 affine -> z2
// 2 subs per node + degree-balanced slot assignment (balance is the ONLY
// change vs r6 -> attributes whether wave imbalance was agg2's cost).
__global__ __launch_bounds__(256) void k_agg2(
    const uint4* __restrict__ u, const int* __restrict__ offs, const int* __restrict__ csr,
    const float* __restrict__ dinv, const float* __restrict__ dsum,
    const float* __restrict__ sc1, const float* __restrict__ sh1,
    uint4* __restrict__ z, int N)
{
  __shared__ int s_len[16];
  __shared__ int s_ord[16];
  int tid = threadIdx.x;
  int m0 = blockIdx.x*16;
  if (tid < 16){
    int n = m0 + tid;
    s_len[tid] = (n < N) ? (offs[n+1] - offs[n]) : -1;
  }
  __syncthreads();
  if (tid < 16){
    int len = s_len[tid];
    int r = 0;
    #pragma unroll
    for (int j = 0; j < 16; j++){
      int lj = s_len[j];
      if (lj > len || (lj == len && j < tid)) r++;
    }
    s_ord[r] = tid;
  }
  __syncthreads();
  int slot = tid >> 4;         // rank 0..15
  int half = (tid >> 3) & 1;
  int lane = tid & 7;
  int node = m0 + s_ord[slot];
  if (node >= N) return;
  int s0 = offs[node], e0 = offs[node+1];
  int mid = s0 + (((e0 - s0) + 1) >> 1);
  int s = half ? mid : s0;
  int e = half ? e0  : mid;
  f32x2 acc[8] = {};
  auto add16 = [&](uint4 v){
    f32x2 p;
    p = __builtin_amdgcn_cvt_pk_f32_fp8((int)v.x, false); acc[0] += p;
    p = __builtin_amdgcn_cvt_pk_f32_fp8((int)v.x, true ); acc[1] += p;
    p = __builtin_amdgcn_cvt_pk_f32_fp8((int)v.y, false); acc[2] += p;
    p = __builtin_amdgcn_cvt_pk_f32_fp8((int)v.y, true ); acc[3] += p;
    p = __builtin_amdgcn_cvt_pk_f32_fp8((int)v.z, false); acc[4] += p;
    p = __builtin_amdgcn_cvt_pk_f32_fp8((int)v.z, true ); acc[5] += p;
    p = __builtin_amdgcn_cvt_pk_f32_fp8((int)v.w, false); acc[6] += p;
    p = __builtin_amdgcn_cvt_pk_f32_fp8((int)v.w, true ); acc[7] += p;
  };
  int i = s;
  for (; i + 4 <= e; i += 4){
    int r0 = csr[i], r1 = csr[i+1], r2 = csr[i+2], r3 = csr[i+3];
    uint4 v0 = u[r0*8 + lane];
    uint4 v1 = u[r1*8 + lane];
    uint4 v2 = u[r2*8 + lane];
    uint4 v3 = u[r3*8 + lane];
    add16(v0); add16(v1); add16(v2); add16(v3);
  }
  for (; i < e; i++) add16(u[csr[i]*8 + lane]);
  if (half == 0) add16(u[node*8 + lane]);

  // combine halves
  #pragma unroll
  for (int j = 0; j < 8; j++){
    acc[j].x += __shfl_xor(acc[j].x, 8);
    acc[j].y += __shfl_xor(acc[j].y, 8);
  }
  if (half != 0) return;

  float d  = dinv[node];
  float ds = dsum[node];
  int f0 = lane*16;
  uint4 o0, o1;
  {
    float4 sa = *(const float4*)(sc1 + f0);
    float4 sb = *(const float4*)(sc1 + f0 + 4);
    float4 ha = *(const float4*)(sh1 + f0);
    float4 hb = *(const float4*)(sh1 + f0 + 4);
    o0.x = pack2bf(d*fmaf(sa.x, acc[0].x, ha.x*ds), d*fmaf(sa.y, acc[0].y, ha.y*ds));
    o0.y = pack2bf(d*fmaf(sa.z, acc[1].x, ha.z*ds), d*fmaf(sa.w, acc[1].y, ha.w*ds));
    o0.z = pack2bf(d*fmaf(sb.x, acc[2].x, hb.x*ds), d*fmaf(sb.y, acc[2].y, hb.y*ds));
    o0.w = pack2bf(d*fmaf(sb.z, acc[3].x, hb.z*ds), d*fmaf(sb.w, acc[3].y, hb.w*ds));
  }
  {
    float4 sa = *(const float4*)(sc1 + f0 + 8);
    float4 sb = *(const float4*)(sc1 + f0 + 12);
    float4 ha = *(const float4*)(sh1 + f0 + 8);
    float4 hb = *(const float4*)(sh1 + f0 + 12);
    o1.x = pack2bf(d*fmaf(sa.x, acc[4].x, ha.x*ds), d*fmaf(sa.y, acc[4].y, ha.y*ds));
    o1.y = pack2bf(d*fmaf(sa.z, acc[5].x, ha.z*ds), d*fmaf(sa.w, acc[5].y, ha.w*ds));
    o1.z = pack2bf(d*fmaf(sb.x, acc[6].x, hb.x*ds), d*fmaf(sb.y, acc[6].y, hb.y*ds));
    o1.w = pack2bf(d*fmaf(sb.z, acc[7].x, hb.z*ds), d*fmaf(sb.w, acc[7].y, hb.w*ds));
  }
  size_t zb = (size_t)(node>>4)*256 + (node&15);
  z[zb + (2*lane)*16]   = o0;
  z[zb + (2*lane+1)*16] = o1;
}

// ---------------- MFMA node GEMM (CTILE columns per block) ----------------
// POOL: grid (mblk, NOUT/CTILE); per-column pool walk bit-identical to full-width version.
template<int K, int NOUT, int CTILE, bool POOL>
__global__ __launch_bounds__(256) void k_gemm_mfma(
    const uint16_t* __restrict__ A, const uint16_t* __restrict__ WTf,
    const float* __restrict__ bias, const int* __restrict__ batch,
    const float* __restrict__ dinv,
    uint8_t* __restrict__ u_out, float* __restrict__ embsum,
    float* __restrict__ gstats, int N)
{
  constexpr int NT = CTILE/16;
  constexpr int KS = K/32;
  constexpr int TRS8 = CTILE + 16;
  constexpr int TRSF = CTILE + 8;
  __shared__ float s_bias[CTILE];
  __shared__ int s_batch[64];
  __shared__ float s_dinv[POOL ? 1 : 64];
  __shared__ float s_sum[POOL ? 1 : CTILE];
  __shared__ float s_sq[POOL ? 1 : CTILE];
  __shared__ float s_trf[POOL ? 64*TRSF : 1];
  __shared__ uint8_t s_tr8[POOL ? 16 : 64*TRS8];
  int tid = threadIdx.x;
  int w = tid >> 6;
  int lane = tid & 63;
  int l15 = lane & 15, quad = lane >> 4;
  int m0 = blockIdx.x * 64;
  int n0 = blockIdx.y * CTILE;
  int tgbase = n0 >> 4;
  for (int i = tid; i < CTILE; i += 256) s_bias[i] = bias[n0 + i];
  if constexpr (!POOL){
    for (int i = tid; i < CTILE; i += 256){ s_sum[i]=0.f; s_sq[i]=0.f; }
    if (tid < 64) s_dinv[tid] = (m0+tid < N) ? dinv[m0+tid] : 0.f;
  }
  if (POOL && tid < 64) s_batch[tid] = (m0+tid < N) ? batch[m0+tid] : -1;
  __syncthreads();

  const uint16_t* Ag = A + (size_t)(m0/16 + w)*(16*K);

  f32x4 acc[NT];
  #pragma unroll
  for (int t=0;t<NT;t++) acc[t] = (f32x4){0.f,0.f,0.f,0.f};

  #pragma unroll
  for (int ks=0; ks<KS; ks++){
    bf16x8 af = *(const bf16x8*)(Ag + (ks*4 + quad)*128 + l15*8);
    #pragma unroll
    for (int t=0;t<NT;t++){
      bf16x8 bw = *(const bf16x8*)(WTf + (((size_t)((tgbase + t)*KS + ks)*64 + lane) << 3));
      acc[t] = __builtin_amdgcn_mfma_f32_16x16x32_bf16(af, bw, acc[t], 0, 0, 0);
    }
  }

  int rloc = w*16 + quad*4;
  if constexpr (POOL){
    #pragma unroll
    for (int t=0;t<NT;t++){
      int n = t*16 + l15;
      float bv = s_bias[n];
      #pragma unroll
      for (int r=0;r<4;r++){
        bool valid = (m0 + rloc + r) < N;
        float val = fmaxf(acc[t][r] + bv, 0.f);
        s_trf[(rloc + r)*TRSF + n] = valid ? val : 0.f;
      }
    }
    __syncthreads();
    if (tid < CTILE){
      int n = tid;
      float vs = 0.f, vq = 0.f;
      int cur = -1; float run = 0.f;
      #pragma unroll 8
      for (int row = 0; row < 64; row++){
        float v = s_trf[row*TRSF + n];
        vs += v; vq += v*v;
        int b = s_batch[row];
        if (b != cur){
          if (cur >= 0 && run != 0.f) atomicAdd(&embsum[(size_t)cur*NOUT + n0 + n], run);
          cur = b; run = v;
        } else run += v;
      }
      if (cur >= 0 && run != 0.f) atomicAdd(&embsum[(size_t)cur*NOUT + n0 + n], run);
      float* gs = gstats + (size_t)(blockIdx.x & (NSLICE-1))*(2*NOUT);
      atomicAdd(&gs[n0 + n], vs);
      atomicAdd(&gs[NOUT + n0 + n], vq);
    }
  } else {
    #pragma unroll
    for (int t=0;t<NT;t++){
      int n = t*16 + l15;
      float bv = s_bias[n];
      float vs = 0.f, vq = 0.f;
      #pragma unroll
      for (int r=0;r<4;r++){
        bool valid = (m0 + rloc + r) < N;
        float val = fmaxf(acc[t][r] + bv, 0.f);
        float o = valid ? val : 0.f;
        vs += o; vq += o*o;
        s_tr8[(rloc + r)*TRS8 + n] = f2fp8(o * s_dinv[rloc + r]);
      }
      vs += __shfl_xor(vs, 16); vs += __shfl_xor(vs, 32);
      vq += __shfl_xor(vq, 16); vq += __shfl_xor(vq, 32);
      if (quad == 0){
        atomicAdd(&s_sum[n], vs);
        atomicAdd(&s_sq[n], vq);
      }
    }
    __syncthreads();
    constexpr int CPR = CTILE/16;
    for (int i = tid; i < 64*CPR; i += 256){
      int row = i / CPR, c = i - row*CPR;
      int grow = m0 + row;
      if (grow < N)
        *(uint4*)(u_out + (size_t)grow*NOUT + n0 + c*16) = *(const uint4*)(s_tr8 + row*TRS8 + c*16);
    }
    float* gs = gstats + (size_t)(blockIdx.x & (NSLICE-1))*(2*NOUT);
    for (int i = tid; i < CTILE; i += 256){
      atomicAdd(&gs[n0 + i], s_sum[i]);
      atomicAdd(&gs[NOUT + n0 + i], s_sq[i]);
    }
  }
}

// ---------------- GEMM (head MLP, fp32), 32-row x 64-col tiles ----------------
template<int K, int NWTOT, bool CONCAT, bool AFFINE, bool EMB>
__global__ __launch_bounds__(256) void k_gemm_mlp(
    const float* __restrict__ A0, const float* __restrict__ A1,
    const float* __restrict__ W,
    const float* __restrict__ scale, const float* __restrict__ shift,
    const int* __restrict__ gstart, const float* __restrict__ esc, const float* __restrict__ esh,
    const float* __restrict__ bias,
    float* __restrict__ out, float* __restrict__ gstats, int nrows)
{
  __shared__ float As[32*69];
  __shared__ float Bs[32*64];
  __shared__ float s_sum[64], s_sq[64];
  int m0 = blockIdx.x*32;
  int n0 = blockIdx.y*64;
  int tid  = threadIdx.x;
  int tcol = tid & 15, trow = tid >> 4;
  float acc[2][4] = {};
  constexpr int NCH = (K + 31) / 32;
  for (int ch = 0; ch < NCH; ch++){
    int kc0 = ch*32;
    {
      int rr = tid >> 3; int k4 = (tid & 7) << 2;
      int row = m0 + rr;
      int kg = kc0 + k4;
      float4 v = {0.f,0.f,0.f,0.f};
      if (row < nrows){
        if constexpr (CONCAT){
          if (kg < 256){
            v = *(const float4*)(A0 + (size_t)row*256 + kg);
            if constexpr (EMB){
              int c = gstart[row+1] - gstart[row];
              if (c > 0){
                float rinv = 1.0f / (float)c;
                float4 scv = *(const float4*)(esc + kg);
                float4 shv = *(const float4*)(esh + kg);
                v.x = fmaf(v.x*rinv, scv.x, shv.x);
                v.y = fmaf(v.y*rinv, scv.y, shv.y);
                v.z = fmaf(v.z*rinv, scv.z, shv.z);
                v.w = fmaf(v.w*rinv, scv.w, shv.w);
              } else { v.x=v.y=v.z=v.w=0.f; }
            }
          }
          else if (kg < 456) v = *(const float4*)(A1 + (size_t)row*200 + (kg-256));
        } else {
          v = *(const float4*)(A0 + (size_t)row*K + kg);
        }
      }
      if constexpr (AFFINE){
        float4 scv = *(const float4*)(scale + kg);
        float4 shv = *(const float4*)(shift + kg);
        v.x = fmaf(v.x, scv.x, shv.x);
        v.y = fmaf(v.y, scv.y, shv.y);
        v.z = fmaf(v.z, scv.z, shv.z);
        v.w = fmaf(v.w, scv.w, shv.w);
      }
      As[(k4+0)*69 + rr] = v.x;
      As[(k4+1)*69 + rr] = v.y;
      As[(k4+2)*69 + rr] = v.z;
      As[(k4+3)*69 + rr] = v.w;
    }
    #pragma unroll
    for (int j = 0; j < 2; j++){
      int fid = tid + j*256;
      int kk = fid >> 4; int c4 = (fid & 15) << 2;
      int kg = kc0 + kk;
      float4 v = {0.f,0.f,0.f,0.f};
      if (kg < K) v = *(const float4*)(W + (size_t)kg*NWTOT + n0 + c4);
      *(float4*)(Bs + kk*64 + c4) = v;
    }
    __syncthreads();
    #pragma unroll
    for (int kk = 0; kk < 32; kk++){
      float4 b = *(const float4*)(Bs + kk*64 + tcol*4);
      float a0 = As[kk*69 + trow*2];
      float a1 = As[kk*69 + trow*2 + 1];
      acc[0][0] = fmaf(a0, b.x, acc[0][0]);
      acc[0][1] = fmaf(a0, b.y, acc[0][1]);
      acc[0][2] = fmaf(a0, b.z, acc[0][2]);
      acc[0][3] = fmaf(a0, b.w, acc[0][3]);
      acc[1][0] = fmaf(a1, b.x, acc[1][0]);
      acc[1][1] = fmaf(a1, b.y, acc[1][1]);
      acc[1][2] = fmaf(a1, b.z, acc[1][2]);
      acc[1][3] = fmaf(a1, b.w, acc[1][3]);
    }
    __syncthreads();
  }
  if (tid < 64){ s_sum[tid] = 0.f; s_sq[tid] = 0.f; }
  __syncthreads();
  float4 bv = *(const float4*)(bias + n0 + tcol*4);
  float psum[4] = {0,0,0,0}, psq[4] = {0,0,0,0};
  #pragma unroll
  for (int r = 0; r < 2; r++){
    int row = m0 + trow*2 + r;
    if (row < nrows){
      float4 o;
      o.x = fmaxf(acc[r][0] + bv.x, 0.f);
      o.y = fmaxf(acc[r][1] + bv.y, 0.f);
      o.z = fmaxf(acc[r][2] + bv.z, 0.f);
      o.w = fmaxf(acc[r][3] + bv.w, 0.f);
      *(float4*)(out + (size_t)row*NWTOT + n0 + tcol*4) = o;
      psum[0] += o.x; psq[0] += o.x*o.x;
      psum[1] += o.y; psq[1] += o.y*o.y;
      psum[2] += o.z; psq[2] += o.z*o.z;
      psum[3] += o.w; psq[3] += o.w*o.w;
    }
  }
  #pragma unroll
  for (int c = 0; c < 4; c++){
    psum[c] += __shfl_xor(psum[c], 16); psum[c] += __shfl_xor(psum[c], 32);
    psq[c]  += __shfl_xor(psq[c], 16);  psq[c]  += __shfl_xor(psq[c], 32);
  }
  if ((tid & 48) == 0){
    int f0 = tcol*4;
    atomicAdd(&s_sum[f0+0], psum[0]); atomicAdd(&s_sq[f0+0], psq[0]);
    atomicAdd(&s_sum[f0+1], psum[1]); atomicAdd(&s_sq[f0+1], psq[1]);
    atomicAdd(&s_sum[f0+2], psum[2]); atomicAdd(&s_sq[f0+2], psq[2]);
    atomicAdd(&s_sum[f0+3], psum[3]); atomicAdd(&s_sq[f0+3], psq[3]);
  }
  __syncthreads();
  float* gs = gstats + (size_t)(blockIdx.x & (NSLICE-1))*(2*NWTOT);
  if (tid < 64){
    atomicAdd(&gs[n0 + tid], s_sum[tid]);
    atomicAdd(&gs[NWTOT + n0 + tid], s_sq[tid]);
  }
}

// ---------------- final ----------------
__global__ __launch_bounds__(256) void k_final(
    const float* __restrict__ a2, const float* __restrict__ sc, const float* __restrict__ sh,
    const float* __restrict__ w, const float* __restrict__ b, float* __restrict__ out, int G)
{
  int gid  = blockIdx.x*blockDim.x + threadIdx.x;
  int wid  = gid >> 6;
  int lane = gid & 63;
  if (wid >= G) return;
  float2 v = ((const float2*)(a2 + (size_t)wid*128))[lane];
  int k = lane*2;
  float s = fmaf(v.x, sc[k], sh[k]) * w[k] + fmaf(v.y, sc[k+1], sh[k+1]) * w[k+1];
  #pragma unroll
  for (int o = 32; o > 0; o >>= 1) s += __shfl_down(s, o, 64);
  if (lane == 0) out[wid] = s + b[0];
}

// ---------------- launcher ----------------
extern "C" void kernel_launch(void* const* d_in, const int* in_sizes, int n_in,
                              void* d_out, int out_size, void* d_ws, size_t ws_size,
                              hipStream_t stream)
{
  (void)n_in; (void)out_size; (void)ws_size;
  const float* x    = (const float*)d_in[0];
  const int*   ei   = (const int*)d_in[1];
  const int*   batch= (const int*)d_in[2];
  const float* rdk  = (const float*)d_in[3];
  const float* W1   = (const float*)d_in[4];
  const float* b1   = (const float*)d_in[5];
  const float* g1   = (const float*)d_in[6];
  const float* be1  = (const float*)d_in[7];
  const float* W2   = (const float*)d_in[8];
  const float* b2   = (const float*)d_in[9];
  const float* g2   = (const float*)d_in[10];
  const float* be2  = (const float*)d_in[11];
  const float* mW1  = (const float*)d_in[12];
  const float* mb1  = (const float*)d_in[13];
  const float* mg1  = (const float*)d_in[14];
  const float* mbe1 = (const float*)d_in[15];
  const float* mW2  = (const float*)d_in[16];
  const float* mb2  = (const float*)d_in[17];
  const float* mg2  = (const float*)d_in[18];
  const float* mbe2 = (const float*)d_in[19];
  const float* mW3  = (const float*)d_in[20];
  const float* mb3  = (const float*)d_in[21];

  const int N = in_sizes[0] / 64;
  const int E = in_sizes[1] / 2;
  const int G = in_sizes[3] / 200;
  const int* erow = ei;
  const int* ecol = ei + E;
  const int nb = (N + BK_SIZE - 1) >> BK_BITS;

  size_t off = 0;
  auto alloc = [&](size_t bytes)->char*{
    char* p = (char*)d_ws + off;
    off += (bytes + 255) & ~(size_t)255;
    return p;
  };
  int*   offs   = (int*)  alloc(((size_t)N+1)*4);
  int*   csr    = (int*)  alloc((size_t)E*4);
  uint32_t* ebuf= (uint32_t*)alloc((size_t)NBK_MAX*EB_CAP*4);
  int*   bcur   = (int*)  alloc(NBK_MAX*4);
  float* dinv   = (float*)alloc((size_t)N*4);
  float* dsum   = (float*)alloc((size_t)N*4);
  uint16_t* xs  = (uint16_t*)alloc((size_t)N*64*2);
  uint16_t* z1  = (uint16_t*)alloc(((size_t)N+16)*64*2);
  uint8_t*  u   = (uint8_t*)alloc((size_t)N*128);
  uint16_t* z2  = (uint16_t*)alloc(((size_t)N+16)*128*2);
  uint16_t* WT1 = (uint16_t*)alloc((size_t)128*64*2);
  uint16_t* WT2 = (uint16_t*)alloc((size_t)256*128*2);
  float* embsum = (float*)alloc((size_t)G*256*4);
  int*   gstart = (int*)  alloc(((size_t)G+1)*4);
  float* a1     = (float*)alloc((size_t)G*256*4);
  float* a2     = (float*)alloc((size_t)G*128*4);
  float* gstats = (float*)alloc((size_t)4*NSLICE*2*256*4);
  float* scsh   = (float*)alloc((size_t)4*2*256*4);

  float* gs0 = gstats;
  float* gs1 = gstats + NSLICE*2*256;
  float* gs2 = gstats + 2*NSLICE*2*256;
  float* gs3 = gstats + 3*NSLICE*2*256;
  float* sc1 = scsh;        float* sh1 = scsh + 256;
  float* sc2 = scsh + 512;  float* sh2 = scsh + 768;
  float* sc3 = scsh + 1024; float* sh3 = scsh + 1280;
  float* sc4 = scsh + 1536; float* sh4 = scsh + 1792;

  int cbN   = (N + 255) / 256;
  int mblk  = (N + 63) / 64;
  int gblk32= (G + 31) / 32;
  int ablk  = (E + PA_TILE - 1) / PA_TILE;

  k_misc<<<1280 + cbN + 1 + 32 + 128, 256, 0, stream>>>(
      batch, gstart, N, G, cbN, W1, WT1, W2, WT2, bcur,
      (float4*)gstats, (float4*)embsum);

  k_passA<<<ablk,256,0,stream>>>(erow, ecol, bcur, ebuf, E);
  k_passB2<<<nb,256,0,stream>>>(ebuf, bcur, offs, dinv, csr, (const float4*)x, (ushort4*)xs, N, E, nb);

  k_agg1<<<(N+7)/8,256,0,stream>>>((const uint4*)xs, offs, csr, dinv, (uint4*)z1, dsum, N);
  k_gemm_mfma<64,128,128,false><<<dim3(mblk,1),256,0,stream>>>(z1, WT1, b1, nullptr, dinv, u, nullptr, gs0, N);
  k_bnfin<<<128,128,0,stream>>>(gs0, 128, 1.0f/(float)N, g1, be1, sc1, sh1);

  k_agg2<<<(N+15)/16,256,0,stream>>>((const uint4*)u, offs, csr, dinv, dsum, sc1, sh1, (uint4*)z2, N);
  k_gemm_mfma<128,256,128,true><<<dim3(mblk,2),256,0,stream>>>(z2, WT2, b2, batch, nullptr, nullptr, embsum, gs1, N);
  k_bnfin<<<256,128,0,stream>>>(gs1, 256, 1.0f/(float)N, g2, be2, sc2, sh2);

  k_gemm_mlp<456,256,true,false,true><<<dim3(gblk32,4),256,0,stream>>>(embsum, rdk, mW1, nullptr, nullptr, gstart, sc2, sh2, mb1, a1, gs2, G);
  k_bnfin<<<256,128,0,stream>>>(gs2, 256, 1.0f/(float)G, mg1, mbe1, sc3, sh3);
  k_gemm_mlp<256,128,false,true,false><<<dim3(gblk32,2),256,0,stream>>>(a1, nullptr, mW2, sc3, sh3, nullptr, nullptr, nullptr, mb2, a2, gs3, G);
  k_bnfin<<<128,128,0,stream>>>(gs3, 128, 1.0f/(float)G, mg2, mbe2, sc4, sh4);
  k_final<<<(G+3)/4,256,0,stream>>>(a2, sc4, sh4, mW3, mb3, (float*)d_out, G);
}

// Round 8
// 441.479 us; speedup vs baseline: 1.0148x; 1.0148x over previous
//
#include <hip/hip_runtime.h>
#include <cstdint>
#include <cstddef>

#define BN_EPS 1e-5f
#define NSLICE 128
#define BK_BITS 7
#define BK_SIZE 128
#define NBK_MAX 1024
#define EB_CAP 5120

typedef __attribute__((ext_vector_type(8))) __bf16 bf16x8;
typedef __attribute__((ext_vector_type(4))) float f32x4;
typedef __attribute__((ext_vector_type(2))) float f32x2;

// ---------------- helpers ----------------

__device__ inline uint16_t f2bf(float f){
  union {float f; uint32_t u;} v; v.f = f;
  uint32_t u = v.u;
  return (uint16_t)((u + 0x7FFFu + ((u >> 16) & 1u)) >> 16);
}

__device__ inline uint32_t pack2bf(float a, float b){
  return (uint32_t)f2bf(a) | ((uint32_t)f2bf(b) << 16);
}

__device__ inline void bf2f2(uint32_t w, float& a, float& b){
  union {uint32_t u; float f;} ua, ub;
  ua.u = w << 16; ub.u = w & 0xFFFF0000u;
  a = ua.f; b = ub.f;
}

// unpack a bf16 pair word into a packed f32x2 (low half, high half)
__device__ inline f32x2 bfpair(uint32_t w){
  union {uint32_t u; float f;} ua, ub;
  ua.u = w << 16; ub.u = w & 0xFFFF0000u;
  return (f32x2){ua.f, ub.f};
}

__device__ inline uint8_t f2fp8(float v){
  uint32_t t = (uint32_t)__builtin_amdgcn_cvt_pk_fp8_f32(v, v, 0, false);
  return (uint8_t)(t & 0xFF);
}

__device__ inline void prepW_body(const float* W, uint16_t* WTf, int K, int NOUT, int id){
  if (id >= K*NOUT) return;
  int j    = id & 7;
  int l    = (id >> 3) & 63;
  int l15  = l & 15, quad = l >> 4;
  int rest = id >> 9;
  int KS   = K >> 5;
  int ks   = rest % KS;
  int t    = rest / KS;
  int k = ks*32 + quad*8 + j;
  int n = t*16 + l15;
  WTf[id] = f2bf(W[(size_t)k*NOUT + n]);
}

// ---------------- fused init ----------------
__global__ __launch_bounds__(256) void k_misc(
    const int* __restrict__ batch, int* __restrict__ gstart, int N, int G, int cbN,
    const float* __restrict__ W1, uint16_t* __restrict__ WT1,
    const float* __restrict__ W2, uint16_t* __restrict__ WT2,
    int* __restrict__ bcur,
    float4* __restrict__ gstats4, float4* __restrict__ embsum4)
{
  int b = blockIdx.x;
  int t = threadIdx.x;
  float4 z4 = {0.f,0.f,0.f,0.f};
  if (b < 256){
    gstats4[b*256 + t] = z4;
  } else if (b < 1280){
    embsum4[(b-256)*256 + t] = z4;
  } else if (b < 1280 + cbN){
    int i = (b-1280)*256 + t;
    if (i < N){
      int bb = batch[i];
      int bp = (i > 0) ? batch[i-1] : -1;
      for (int g = bp+1; g <= bb; g++) gstart[g] = i;
      if (i == N-1){
        for (int g = bb+1; g <= G; g++) gstart[g] = N;
      }
    }
  } else if (b == 1280 + cbN){
    for (int i = t; i < NBK_MAX; i += 256) bcur[i] = i * EB_CAP;
  } else if (b < 1280 + cbN + 1 + 32){
    prepW_body(W1, WT1, 64, 128, (b - 1280 - cbN - 1)*256 + t);
  } else {
    prepW_body(W2, WT2, 128, 256, (b - 1280 - cbN - 33)*256 + t);
  }
}

// ---------------- graph preprocessing: 128-node buckets, single-phase passA ----------------
#define PA_TILE 4096

__global__ __launch_bounds__(256) void k_passA(
    const int* __restrict__ row, const int* __restrict__ col,
    int* __restrict__ bcur, uint32_t* __restrict__ ebuf, int E)
{
  __shared__ int hist[NBK_MAX];
  __shared__ int rbase[NBK_MAX];
  int t = threadIdx.x;
  int start = blockIdx.x * PA_TILE;
  for (int i = t; i < NBK_MAX; i += 256) hist[i] = 0;
  __syncthreads();
  uint32_t myv[16]; int myb[16];
  #pragma unroll
  for (int j = 0; j < 16; j++){
    int e = start + t + j*256;
    if (e < E){
      int r = row[e], c = col[e];
      myb[j] = c >> BK_BITS;
      myv[j] = ((uint32_t)r << BK_BITS) | (uint32_t)(c & (BK_SIZE-1));
      atomicAdd(&hist[myb[j]], 1);
    } else myb[j] = -1;
  }
  __syncthreads();
  for (int i = t; i < NBK_MAX; i += 256){
    int h = hist[i];
    rbase[i] = (h > 0) ? atomicAdd(&bcur[i], h) : 0;
  }
  __syncthreads();
  for (int i = t; i < NBK_MAX; i += 256) hist[i] = 0;
  __syncthreads();
  #pragma unroll
  for (int j = 0; j < 16; j++){
    if (myb[j] >= 0){
      int pos = rbase[myb[j]] + atomicAdd(&hist[myb[j]], 1);
      ebuf[pos] = myv[j];
    }
  }
}

// passB2 (128-node buckets) + inlined bucket-prefix scan + fused x->xs conversion
__global__ __launch_bounds__(256) void k_passB2(
    const uint32_t* __restrict__ ebuf, const int* __restrict__ bcur,
    int* __restrict__ offs, float* __restrict__ dinv,
    int* __restrict__ csr,
    const float4* __restrict__ x, ushort4* __restrict__ xs,
    int N, int E, int nb)
{
  __shared__ int deg[BK_SIZE];
  __shared__ int cur[BK_SIZE];
  __shared__ int ps[BK_SIZE];
  __shared__ int red[256];
  int b = blockIdx.x;
  int base = b << BK_BITS;
  int t = threadIdx.x;
  // inline scan: s = sum of counts of buckets < b
  int partial = 0;
  for (int i = t; i < NBK_MAX; i += 256){
    int cnt = bcur[i] - i*EB_CAP;
    if (i < b) partial += cnt;
  }
  red[t] = partial;
  if (t < BK_SIZE) deg[t] = 0;
  __syncthreads();
  for (int off = 128; off > 0; off >>= 1){
    if (t < off) red[t] += red[t+off];
    __syncthreads();
  }
  int s = red[0];
  int ecnt = bcur[b] - b*EB_CAP;
  const uint32_t* eb = ebuf + (size_t)b*EB_CAP;
  for (int i = t; i < ecnt; i += 256)
    atomicAdd(&deg[eb[i] & (BK_SIZE-1u)], 1);
  __syncthreads();
  int d = (t < BK_SIZE) ? deg[t] : 0;
  if (t < BK_SIZE) ps[t] = d;
  __syncthreads();
  for (int off=1; off<BK_SIZE; off<<=1){
    int x_ = 0;
    if (t < BK_SIZE && t >= off) x_ = ps[t-off];
    __syncthreads();
    if (t < BK_SIZE && t >= off) ps[t] += x_;
    __syncthreads();
  }
  if (t < BK_SIZE){
    int o = s + ps[t] - d;
    cur[t] = o;
    int n0 = base + t;
    if (n0 < N){ offs[n0] = o; dinv[n0] = 1.0f / sqrtf((float)(d + 1)); }
  }
  if (b == nb-1 && t == 0) offs[N] = E;
  __syncthreads();
  for (int i = t; i < ecnt; i += 256){
    uint32_t v = eb[i];
    int local = v & (BK_SIZE-1u);
    int pos = atomicAdd(&cur[local], 1);
    csr[pos] = (int)(v >> BK_BITS);
  }
  for (int idx = t; idx < BK_SIZE*16; idx += 256){
    int local = idx >> 4;
    int node = base + local;
    if (node < N){
      float dd = 1.0f / sqrtf((float)(deg[local] + 1));
      int c16 = idx & 15;
      float4 v = x[(size_t)node*16 + c16];
      ushort4 o;
      o.x = f2bf(v.x*dd); o.y = f2bf(v.y*dd); o.z = f2bf(v.z*dd); o.w = f2bf(v.w*dd);
      xs[(size_t)node*16 + c16] = o;
    }
  }
}

// parallel bn finalize: one block per column, slice-parallel tree reduce
__global__ __launch_bounds__(128) void k_bnfin(const float* __restrict__ region, int F, float invCount,
                        const float* __restrict__ g, const float* __restrict__ be,
                        float* __restrict__ scale, float* __restrict__ shift){
  __shared__ float ss[128], sq[128];
  int i  = blockIdx.x;
  int sl = threadIdx.x;
  ss[sl] = region[sl*2*F + i];
  sq[sl] = region[sl*2*F + F + i];
  __syncthreads();
  for (int off = 64; off > 0; off >>= 1){
    if (sl < off){ ss[sl] += ss[sl+off]; sq[sl] += sq[sl+off]; }
    __syncthreads();
  }
  if (sl == 0){
    float mu  = ss[0] * invCount;
    float var = sq[0] * invCount - mu*mu;
    if (var < 0.f) var = 0.f;
    float rstd = 1.0f / sqrtf(var + BN_EPS);
    float sc = g[i] * rstd;
    scale[i] = sc;
    shift[i] = be[i] - mu * sc;
  }
}

// ---------------- aggregation kernels ----------------
// agg1: 4 subs per node (quarter ranges x 8 lanes, 8 nodes/block), NO balance
// permutation (r7: balance on agg2 cost +6us -> reverted everywhere; this
// round isolates split-degree from balance on agg1).
// (History: cross-iteration row pipelines spill to scratch (r2/r3, 2.2x);
// nontemporal csr refetches +24MB (r5). 2-way split was +21% on agg1 (r6).)
__global__ __launch_bounds__(256) void k_agg1(
    const uint4* __restrict__ xs, const int* __restrict__ offs, const int* __restrict__ csr,
    const float* __restrict__ dinv, uint4* __restrict__ z, float* __restrict__ dsum, int N)
{
  int tid     = threadIdx.x;
  int slot    = tid >> 5;        // 8 nodes/block
  int quarter = (tid >> 3) & 3;  // quarter of the edge list
  int lane    = tid & 7;         // 16B column within the 128B row
  int node = blockIdx.x*8 + slot;
  if (node >= N) return;
  int s0 = offs[node], e0 = offs[node+1];
  int len = e0 - s0;
  int q = len >> 2, rem = len & 3;
  int s = s0 + quarter*q + (quarter < rem ? quarter : rem);
  int e = s + q + (quarter < rem ? 1 : 0);

  f32x2 acc[4] = {};
  float ds = 0.f;
  auto add8 = [&](uint4 v){
    acc[0] += bfpair(v.x); acc[1] += bfpair(v.y);
    acc[2] += bfpair(v.z); acc[3] += bfpair(v.w);
  };
  int i = s;
  for (; i + 4 <= e; i += 4){
    int r0 = csr[i], r1 = csr[i+1], r2 = csr[i+2], r3 = csr[i+3];
    uint4 v0 = xs[r0*8 + lane];
    uint4 v1 = xs[r1*8 + lane];
    uint4 v2 = xs[r2*8 + lane];
    uint4 v3 = xs[r3*8 + lane];
    add8(v0); add8(v1); add8(v2); add8(v3);
    if (lane == 0) ds += dinv[r0] + dinv[r1] + dinv[r2] + dinv[r3];
  }
  for (; i < e; i++){
    int r0 = csr[i];
    add8(xs[r0*8 + lane]);
    if (lane == 0) ds += dinv[r0];
  }
  float d = dinv[node];
  if (quarter == 0){
    add8(xs[node*8 + lane]);           // self loop once
    if (lane == 0) ds += d;
  }
  // combine quarters: xor 8 then xor 16 (within the 32-lane node group)
  #pragma unroll
  for (int j = 0; j < 4; j++){
    acc[j].x += __shfl_xor(acc[j].x, 8);
    acc[j].y += __shfl_xor(acc[j].y, 8);
    acc[j].x += __shfl_xor(acc[j].x, 16);
    acc[j].y += __shfl_xor(acc[j].y, 16);
  }
  ds += __shfl_xor(ds, 8);
  ds += __shfl_xor(ds, 16);
  if (quarter == 0){
    if (lane == 0) dsum[node] = ds;
    uint4 o;
    o.x = pack2bf(acc[0].x*d, acc[0].y*d);
    o.y = pack2bf(acc[1].x*d, acc[1].y*d);
    o.z = pack2bf(acc[2].x*d, acc[2].y*d);
    o.w = pack2bf(acc[3].x*d, acc[3].y*d);
    z[(node>>4)*128 + lane*16 + (node&15)] = o;
  }
}

// agg2: gather u (fp8, 16B/lane, 8 lanes/node) -> algebraic bn1 affine -> z2
// r6 2-way geometry (no balance), plus SPLIT EPILOGUE: after the combine
// shuffle both halves hold the full accumulator, so half 0 computes/stores
// o0 and half 1 computes/stores o1 (r6 idled half the wave through the
// ~40-inst epilogue). Half-selection via per-thread-uniform ternaries, not
// runtime array indexing (which would allocate acc in scratch).
__global__ __launch_bounds__(256) void k_agg2(
    const uint4* __restrict__ u, const int* __restrict__ offs, const int* __restrict__ csr,
    const float* __restrict__ dinv, const float* __restrict__ dsum,
    const float* __restrict__ sc1, const float* __restrict__ sh1,
    uint4* __restrict__ z, int N)
{
  int tid  = threadIdx.x;
  int sub16= tid >> 4;
  int half = (tid >> 3) & 1;
  int lane = tid & 7;
  int node = blockIdx.x*16 + sub16;
  if (node >= N) return;
  int s0 = offs[node], e0 = offs[node+1];
  int mid = s0 + (((e0 - s0) + 1) >> 1);
  int s = half ? mid : s0;
  int e = half ? e0  : mid;
  f32x2 acc[8] = {};
  auto add16 = [&](uint4 v){
    f32x2 p;
    p = __builtin_amdgcn_cvt_pk_f32_fp8((int)v.x, false); acc[0] += p;
    p = __builtin_amdgcn_cvt_pk_f32_fp8((int)v.x, true ); acc[1] += p;
    p = __builtin_amdgcn_cvt_pk_f32_fp8((int)v.y, false); acc[2] += p;
    p = __builtin_amdgcn_cvt_pk_f32_fp8((int)v.y, true ); acc[3] += p;
    p = __builtin_amdgcn_cvt_pk_f32_fp8((int)v.z, false); acc[4] += p;
    p = __builtin_amdgcn_cvt_pk_f32_fp8((int)v.z, true ); acc[5] += p;
    p = __builtin_amdgcn_cvt_pk_f32_fp8((int)v.w, false); acc[6] += p;
    p = __builtin_amdgcn_cvt_pk_f32_fp8((int)v.w, true ); acc[7] += p;
  };
  int i = s;
  for (; i + 4 <= e; i += 4){
    int r0 = csr[i], r1 = csr[i+1], r2 = csr[i+2], r3 = csr[i+3];
    uint4 v0 = u[r0*8 + lane];
    uint4 v1 = u[r1*8 + lane];
    uint4 v2 = u[r2*8 + lane];
    uint4 v3 = u[r3*8 + lane];
    add16(v0); add16(v1); add16(v2); add16(v3);
  }
  for (; i < e; i++) add16(u[csr[i]*8 + lane]);
  if (half == 0) add16(u[node*8 + lane]);

  // combine halves: both halves end with the full 16-feature accumulator
  #pragma unroll
  for (int j = 0; j < 8; j++){
    acc[j].x += __shfl_xor(acc[j].x, 8);
    acc[j].y += __shfl_xor(acc[j].y, 8);
  }

  float d  = dinv[node];
  float ds = dsum[node];
  // half 0 -> features [lane*16, lane*16+8) (o0 slot); half 1 -> +8 (o1 slot)
  int f0 = lane*16 + half*8;
  f32x2 a0 = half ? acc[4] : acc[0];
  f32x2 a1 = half ? acc[5] : acc[1];
  f32x2 a2 = half ? acc[6] : acc[2];
  f32x2 a3 = half ? acc[7] : acc[3];
  float4 sa = *(const float4*)(sc1 + f0);
  float4 sb = *(const float4*)(sc1 + f0 + 4);
  float4 ha = *(const float4*)(sh1 + f0);
  float4 hb = *(const float4*)(sh1 + f0 + 4);
  uint4 o;
  o.x = pack2bf(d*fmaf(sa.x, a0.x, ha.x*ds), d*fmaf(sa.y, a0.y, ha.y*ds));
  o.y = pack2bf(d*fmaf(sa.z, a1.x, ha.z*ds), d*fmaf(sa.w, a1.y, ha.w*ds));
  o.z = pack2bf(d*fmaf(sb.x, a2.x, hb.x*ds), d*fmaf(sb.y, a2.y, hb.y*ds));
  o.w = pack2bf(d*fmaf(sb.z, a3.x, hb.z*ds), d*fmaf(sb.w, a3.y, hb.w*ds));
  size_t zb = (size_t)(node>>4)*256 + (node&15);
  z[zb + (size_t)(2*lane + half)*16] = o;
}

// ---------------- MFMA node GEMM (CTILE columns per block) ----------------
// POOL: grid (mblk, NOUT/CTILE); per-column pool walk bit-identical to full-width version.
template<int K, int NOUT, int CTILE, bool POOL>
__global__ __launch_bounds__(256) void k_gemm_mfma(
    const uint16_t* __restrict__ A, const uint16_t* __restrict__ WTf,
    const float* __restrict__ bias, const int* __restrict__ batch,
    const float* __restrict__ dinv,
    uint8_t* __restrict__ u_out, float* __restrict__ embsum,
    float* __restrict__ gstats, int N)
{
  constexpr int NT = CTILE/16;
  constexpr int KS = K/32;
  constexpr int TRS8 = CTILE + 16;
  constexpr int TRSF = CTILE + 8;
  __shared__ float s_bias[CTILE];
  __shared__ int s_batch[64];
  __shared__ float s_dinv[POOL ? 1 : 64];
  __shared__ float s_sum[POOL ? 1 : CTILE];
  __shared__ float s_sq[POOL ? 1 : CTILE];
  __shared__ float s_trf[POOL ? 64*TRSF : 1];
  __shared__ uint8_t s_tr8[POOL ? 16 : 64*TRS8];
  int tid = threadIdx.x;
  int w = tid >> 6;
  int lane = tid & 63;
  int l15 = lane & 15, quad = lane >> 4;
  int m0 = blockIdx.x * 64;
  int n0 = blockIdx.y * CTILE;
  int tgbase = n0 >> 4;
  for (int i = tid; i < CTILE; i += 256) s_bias[i] = bias[n0 + i];
  if constexpr (!POOL){
    for (int i = tid; i < CTILE; i += 256){ s_sum[i]=0.f; s_sq[i]=0.f; }
    if (tid < 64) s_dinv[tid] = (m0+tid < N) ? dinv[m0+tid] : 0.f;
  }
  if (POOL && tid < 64) s_batch[tid] = (m0+tid < N) ? batch[m0+tid] : -1;
  __syncthreads();

  const uint16_t* Ag = A + (size_t)(m0/16 + w)*(16*K);

  f32x4 acc[NT];
  #pragma unroll
  for (int t=0;t<NT;t++) acc[t] = (f32x4){0.f,0.f,0.f,0.f};

  #pragma unroll
  for (int ks=0; ks<KS; ks++){
    bf16x8 af = *(const bf16x8*)(Ag + (ks*4 + quad)*128 + l15*8);
    #pragma unroll
    for (int t=0;t<NT;t++){
      bf16x8 bw = *(const bf16x8*)(WTf + (((size_t)((tgbase + t)*KS + ks)*64 + lane) << 3));
      acc[t] = __builtin_amdgcn_mfma_f32_16x16x32_bf16(af, bw, acc[t], 0, 0, 0);
    }
  }

  int rloc = w*16 + quad*4;
  if constexpr (POOL){
    #pragma unroll
    for (int t=0;t<NT;t++){
      int n = t*16 + l15;
      float bv = s_bias[n];
      #pragma unroll
      for (int r=0;r<4;r++){
        bool valid = (m0 + rloc + r) < N;
        float val = fmaxf(acc[t][r] + bv, 0.f);
        s_trf[(rloc + r)*TRSF + n] = valid ? val : 0.f;
      }
    }
    __syncthreads();
    if (tid < CTILE){
      int n = tid;
      float vs = 0.f, vq = 0.f;
      int cur = -1; float run = 0.f;
      #pragma unroll 8
      for (int row = 0; row < 64; row++){
        float v = s_trf[row*TRSF + n];
        vs += v; vq += v*v;
        int b = s_batch[row];
        if (b != cur){
          if (cur >= 0 && run != 0.f) atomicAdd(&embsum[(size_t)cur*NOUT + n0 + n], run);
          cur = b; run = v;
        } else run += v;
      }
      if (cur >= 0 && run != 0.f) atomicAdd(&embsum[(size_t)cur*NOUT + n0 + n], run);
      float* gs = gstats + (size_t)(blockIdx.x & (NSLICE-1))*(2*NOUT);
      atomicAdd(&gs[n0 + n], vs);
      atomicAdd(&gs[NOUT + n0 + n], vq);
    }
  } else {
    #pragma unroll
    for (int t=0;t<NT;t++){
      int n = t*16 + l15;
      float bv = s_bias[n];
      float vs = 0.f, vq = 0.f;
      #pragma unroll
      for (int r=0;r<4;r++){
        bool valid = (m0 + rloc + r) < N;
        float val = fmaxf(acc[t][r] + bv, 0.f);
        float o = valid ? val : 0.f;
        vs += o; vq += o*o;
        s_tr8[(rloc + r)*TRS8 + n] = f2fp8(o * s_dinv[rloc + r]);
      }
      vs += __shfl_xor(vs, 16); vs += __shfl_xor(vs, 32);
      vq += __shfl_xor(vq, 16); vq += __shfl_xor(vq, 32);
      if (quad == 0){
        atomicAdd(&s_sum[n], vs);
        atomicAdd(&s_sq[n], vq);
      }
    }
    __syncthreads();
    constexpr int CPR = CTILE/16;
    for (int i = tid; i < 64*CPR; i += 256){
      int row = i / CPR, c = i - row*CPR;
      int grow = m0 + row;
      if (grow < N)
        *(uint4*)(u_out + (size_t)grow*NOUT + n0 + c*16) = *(const uint4*)(s_tr8 + row*TRS8 + c*16);
    }
    float* gs = gstats + (size_t)(blockIdx.x & (NSLICE-1))*(2*NOUT);
    for (int i = tid; i < CTILE; i += 256){
      atomicAdd(&gs[n0 + i], s_sum[i]);
      atomicAdd(&gs[NOUT + n0 + i], s_sq[i]);
    }
  }
}

// ---------------- GEMM (head MLP, fp32), 32-row x 64-col tiles ----------------
template<int K, int NWTOT, bool CONCAT, bool AFFINE, bool EMB>
__global__ __launch_bounds__(256) void k_gemm_mlp(
    const float* __restrict__ A0, const float* __restrict__ A1,
    const float* __restrict__ W,
    const float* __restrict__ scale, const float* __restrict__ shift,
    const int* __restrict__ gstart, const float* __restrict__ esc, const float* __restrict__ esh,
    const float* __restrict__ bias,
    float* __restrict__ out, float* __restrict__ gstats, int nrows)
{
  __shared__ float As[32*69];
  __shared__ float Bs[32*64];
  __shared__ float s_sum[64], s_sq[64];
  int m0 = blockIdx.x*32;
  int n0 = blockIdx.y*64;
  int tid  = threadIdx.x;
  int tcol = tid & 15, trow = tid >> 4;
  float acc[2][4] = {};
  constexpr int NCH = (K + 31) / 32;
  for (int ch = 0; ch < NCH; ch++){
    int kc0 = ch*32;
    {
      int rr = tid >> 3; int k4 = (tid & 7) << 2;
      int row = m0 + rr;
      int kg = kc0 + k4;
      float4 v = {0.f,0.f,0.f,0.f};
      if (row < nrows){
        if constexpr (CONCAT){
          if (kg < 256){
            v = *(const float4*)(A0 + (size_t)row*256 + kg);
            if constexpr (EMB){
              int c = gstart[row+1] - gstart[row];
              if (c > 0){
                float rinv = 1.0f / (float)c;
                float4 scv = *(const float4*)(esc + kg);
                float4 shv = *(const float4*)(esh + kg);
                v.x = fmaf(v.x*rinv, scv.x, shv.x);
                v.y = fmaf(v.y*rinv, scv.y, shv.y);
                v.z = fmaf(v.z*rinv, scv.z, shv.z);
                v.w = fmaf(v.w*rinv, scv.w, shv.w);
              } else { v.x=v.y=v.z=v.w=0.f; }
            }
          }
          else if (kg < 456) v = *(const float4*)(A1 + (size_t)row*200 + (kg-256));
        } else {
          v = *(const float4*)(A0 + (size_t)row*K + kg);
        }
      }
      if constexpr (AFFINE){
        float4 scv = *(const float4*)(scale + kg);
        float4 shv = *(const float4*)(shift + kg);
        v.x = fmaf(v.x, scv.x, shv.x);
        v.y = fmaf(v.y, scv.y, shv.y);
        v.z = fmaf(v.z, scv.z, shv.z);
        v.w = fmaf(v.w, scv.w, shv.w);
      }
      As[(k4+0)*69 + rr] = v.x;
      As[(k4+1)*69 + rr] = v.y;
      As[(k4+2)*69 + rr] = v.z;
      As[(k4+3)*69 + rr] = v.w;
    }
    #pragma unroll
    for (int j = 0; j < 2; j++){
      int fid = tid + j*256;
      int kk = fid >> 4; int c4 = (fid & 15) << 2;
      int kg = kc0 + kk;
      float4 v = {0.f,0.f,0.f,0.f};
      if (kg < K) v = *(const float4*)(W + (size_t)kg*NWTOT + n0 + c4);
      *(float4*)(Bs + kk*64 + c4) = v;
    }
    __syncthreads();
    #pragma unroll
    for (int kk = 0; kk < 32; kk++){
      float4 b = *(const float4*)(Bs + kk*64 + tcol*4);
      float a0 = As[kk*69 + trow*2];
      float a1 = As[kk*69 + trow*2 + 1];
      acc[0][0] = fmaf(a0, b.x, acc[0][0]);
      acc[0][1] = fmaf(a0, b.y, acc[0][1]);
      acc[0][2] = fmaf(a0, b.z, acc[0][2]);
      acc[0][3] = fmaf(a0, b.w, acc[0][3]);
      acc[1][0] = fmaf(a1, b.x, acc[1][0]);
      acc[1][1] = fmaf(a1, b.y, acc[1][1]);
      acc[1][2] = fmaf(a1, b.z, acc[1][2]);
      acc[1][3] = fmaf(a1, b.w, acc[1][3]);
    }
    __syncthreads();
  }
  if (tid < 64){ s_sum[tid] = 0.f; s_sq[tid] = 0.f; }
  __syncthreads();
  float4 bv = *(const float4*)(bias + n0 + tcol*4);
  float psum[4] = {0,0,0,0}, psq[4] = {0,0,0,0};
  #pragma unroll
  for (int r = 0; r < 2; r++){
    int row = m0 + trow*2 + r;
    if (row < nrows){
      float4 o;
      o.x = fmaxf(acc[r][0] + bv.x, 0.f);
      o.y = fmaxf(acc[r][1] + bv.y, 0.f);
      o.z = fmaxf(acc[r][2] + bv.z, 0.f);
      o.w = fmaxf(acc[r][3] + bv.w, 0.f);
      *(float4*)(out + (size_t)row*NWTOT + n0 + tcol*4) = o;
      psum[0] += o.x; psq[0] += o.x*o.x;
      psum[1] += o.y; psq[1] += o.y*o.y;
      psum[2] += o.z; psq[2] += o.z*o.z;
      psum[3] += o.w; psq[3] += o.w*o.w;
    }
  }
  #pragma unroll
  for (int c = 0; c < 4; c++){
    psum[c] += __shfl_xor(psum[c], 16); psum[c] += __shfl_xor(psum[c], 32);
    psq[c]  += __shfl_xor(psq[c], 16);  psq[c]  += __shfl_xor(psq[c], 32);
  }
  if ((tid & 48) == 0){
    int f0 = tcol*4;
    atomicAdd(&s_sum[f0+0], psum[0]); atomicAdd(&s_sq[f0+0], psq[0]);
    atomicAdd(&s_sum[f0+1], psum[1]); atomicAdd(&s_sq[f0+1], psq[1]);
    atomicAdd(&s_sum[f0+2], psum[2]); atomicAdd(&s_sq[f0+2], psq[2]);
    atomicAdd(&s_sum[f0+3], psum[3]); atomicAdd(&s_sq[f0+3], psq[3]);
  }
  __syncthreads();
  float* gs = gstats + (size_t)(blockIdx.x & (NSLICE-1))*(2*NWTOT);
  if (tid < 64){
    atomicAdd(&gs[n0 + tid], s_sum[tid]);
    atomicAdd(&gs[NWTOT + n0 + tid], s_sq[tid]);
  }
}

// ---------------- final ----------------
__global__ __launch_bounds__(256) void k_final(
    const float* __restrict__ a2, const float* __restrict__ sc, const float* __restrict__ sh,
    const float* __restrict__ w, const float* __restrict__ b, float* __restrict__ out, int G)
{
  int gid  = blockIdx.x*blockDim.x + threadIdx.x;
  int wid  = gid >> 6;
  int lane = gid & 63;
  if (wid >= G) return;
  float2 v = ((const float2*)(a2 + (size_t)wid*128))[lane];
  int k = lane*2;
  float s = fmaf(v.x, sc[k], sh[k]) * w[k] + fmaf(v.y, sc[k+1], sh[k+1]) * w[k+1];
  #pragma unroll
  for (int o = 32; o > 0; o >>= 1) s += __shfl_down(s, o, 64);
  if (lane == 0) out[wid] = s + b[0];
}

// ---------------- launcher ----------------
extern "C" void kernel_launch(void* const* d_in, const int* in_sizes, int n_in,
                              void* d_out, int out_size, void* d_ws, size_t ws_size,
                              hipStream_t stream)
{
  (void)n_in; (void)out_size; (void)ws_size;
  const float* x    = (const float*)d_in[0];
  const int*   ei   = (const int*)d_in[1];
  const int*   batch= (const int*)d_in[2];
  const float* rdk  = (const float*)d_in[3];
  const float* W1   = (const float*)d_in[4];
  const float* b1   = (const float*)d_in[5];
  const float* g1   = (const float*)d_in[6];
  const float* be1  = (const float*)d_in[7];
  const float* W2   = (const float*)d_in[8];
  const float* b2   = (const float*)d_in[9];
  const float* g2   = (const float*)d_in[10];
  const float* be2  = (const float*)d_in[11];
  const float* mW1  = (const float*)d_in[12];
  const float* mb1  = (const float*)d_in[13];
  const float* mg1  = (const float*)d_in[14];
  const float* mbe1 = (const float*)d_in[15];
  const float* mW2  = (const float*)d_in[16];
  const float* mb2  = (const float*)d_in[17];
  const float* mg2  = (const float*)d_in[18];
  const float* mbe2 = (const float*)d_in[19];
  const float* mW3  = (const float*)d_in[20];
  const float* mb3  = (const float*)d_in[21];

  const int N = in_sizes[0] / 64;
  const int E = in_sizes[1] / 2;
  const int G = in_sizes[3] / 200;
  const int* erow = ei;
  const int* ecol = ei + E;
  const int nb = (N + BK_SIZE - 1) >> BK_BITS;

  size_t off = 0;
  auto alloc = [&](size_t bytes)->char*{
    char* p = (char*)d_ws + off;
    off += (bytes + 255) & ~(size_t)255;
    return p;
  };
  int*   offs   = (int*)  alloc(((size_t)N+1)*4);
  int*   csr    = (int*)  alloc((size_t)E*4);
  uint32_t* ebuf= (uint32_t*)alloc((size_t)NBK_MAX*EB_CAP*4);
  int*   bcur   = (int*)  alloc(NBK_MAX*4);
  float* dinv   = (float*)alloc((size_t)N*4);
  float* dsum   = (float*)alloc((size_t)N*4);
  uint16_t* xs  = (uint16_t*)alloc((size_t)N*64*2);
  uint16_t* z1  = (uint16_t*)alloc(((size_t)N+16)*64*2);
  uint8_t*  u   = (uint8_t*)alloc((size_t)N*128);
  uint16_t* z2  = (uint16_t*)alloc(((size_t)N+16)*128*2);
  uint16_t* WT1 = (uint16_t*)alloc((size_t)128*64*2);
  uint16_t* WT2 = (uint16_t*)alloc((size_t)256*128*2);
  float* embsum = (float*)alloc((size_t)G*256*4);
  int*   gstart = (int*)  alloc(((size_t)G+1)*4);
  float* a1     = (float*)alloc((size_t)G*256*4);
  float* a2     = (float*)alloc((size_t)G*128*4);
  float* gstats = (float*)alloc((size_t)4*NSLICE*2*256*4);
  float* scsh   = (float*)alloc((size_t)4*2*256*4);

  float* gs0 = gstats;
  float* gs1 = gstats + NSLICE*2*256;
  float* gs2 = gstats + 2*NSLICE*2*256;
  float* gs3 = gstats + 3*NSLICE*2*256;
  float* sc1 = scsh;        float* sh1 = scsh + 256;
  float* sc2 = scsh + 512;  float* sh2 = scsh + 768;
  float* sc3 = scsh + 1024; float* sh3 = scsh + 1280;
  float* sc4 = scsh + 1536; float* sh4 = scsh + 1792;

  int cbN   = (N + 255) / 256;
  int mblk  = (N + 63) / 64;
  int gblk32= (G + 31) / 32;
  int ablk  = (E + PA_TILE - 1) / PA_TILE;

  k_misc<<<1280 + cbN + 1 + 32 + 128, 256, 0, stream>>>(
      batch, gstart, N, G, cbN, W1, WT1, W2, WT2, bcur,
      (float4*)gstats, (float4*)embsum);

  k_passA<<<ablk,256,0,stream>>>(erow, ecol, bcur, ebuf, E);
  k_passB2<<<nb,256,0,stream>>>(ebuf, bcur, offs, dinv, csr, (const float4*)x, (ushort4*)xs, N, E, nb);

  k_agg1<<<(N+7)/8,256,0,stream>>>((const uint4*)xs, offs, csr, dinv, (uint4*)z1, dsum, N);
  k_gemm_mfma<64,128,128,false><<<dim3(mblk,1),256,0,stream>>>(z1, WT1, b1, nullptr, dinv, u, nullptr, gs0, N);
  k_bnfin<<<128,128,0,stream>>>(gs0, 128, 1.0f/(float)N, g1, be1, sc1, sh1);

  k_agg2<<<(N+15)/16,256,0,stream>>>((const uint4*)u, offs, csr, dinv, dsum, sc1, sh1, (uint4*)z2, N);
  k_gemm_mfma<128,256,128,true><<<dim3(mblk,2),256,0,stream>>>(z2, WT2, b2, batch, nullptr, nullptr, embsum, gs1, N);
  k_bnfin<<<256,128,0,stream>>>(gs1, 256, 1.0f/(float)N, g2, be2, sc2, sh2);

  k_gemm_mlp<456,256,true,false,true><<<dim3(gblk32,4),256,0,stream>>>(embsum, rdk, mW1, nullptr, nullptr, gstart, sc2, sh2, mb1, a1, gs2, G);
  k_bnfin<<<256,128,0,stream>>>(gs2, 256, 1.0f/(float)G, mg1, mbe1, sc3, sh3);
  k_gemm_mlp<256,128,false,true,false><<<dim3(gblk32,2),256,0,stream>>>(a1, nullptr, mW2, sc3, sh3, nullptr, nullptr, nullptr, mb2, a2, gs3, G);
  k_bnfin<<<128,128,0,stream>>>(gs3, 128, 1.0f/(float)G, mg2, mbe2, sc4, sh4);
  k_final<<<(G+3)/4,256,0,stream>>>(a2, sc4, sh4, mW3, mb3, (float*)d_out, G);
}

// Round 9
// 431.970 us; speedup vs baseline: 1.0371x; 1.0220x over previous
//
#include <hip/hip_runtime.h>
#include <cstdint>
#include <cstddef>

#define BN_EPS 1e-5f
#define NSLICE 128
#define BK_BITS 7
#define BK_SIZE 128
#define NBK_MAX 1024
#define EB_CAP 5120

typedef __attribute__((ext_vector_type(8))) __bf16 bf16x8;
typedef __attribute__((ext_vector_type(4))) float f32x4;
typedef __attribute__((ext_vector_type(2))) float f32x2;

// ---------------- helpers ----------------

__device__ inline uint16_t f2bf(float f){
  union {float f; uint32_t u;} v; v.f = f;
  uint32_t u = v.u;
  return (uint16_t)((u + 0x7FFFu + ((u >> 16) & 1u)) >> 16);
}

__device__ inline uint32_t pack2bf(float a, float b){
  return (uint32_t)f2bf(a) | ((uint32_t)f2bf(b) << 16);
}

__device__ inline void bf2f2(uint32_t w, float& a, float& b){
  union {uint32_t u; float f;} ua, ub;
  ua.u = w << 16; ub.u = w & 0xFFFF0000u;
  a = ua.f; b = ub.f;
}

// unpack a bf16 pair word into a packed f32x2 (low half, high half)
__device__ inline f32x2 bfpair(uint32_t w){
  union {uint32_t u; float f;} ua, ub;
  ua.u = w << 16; ub.u = w & 0xFFFF0000u;
  return (f32x2){ua.f, ub.f};
}

__device__ inline uint8_t f2fp8(float v){
  uint32_t t = (uint32_t)__builtin_amdgcn_cvt_pk_fp8_f32(v, v, 0, false);
  return (uint8_t)(t & 0xFF);
}

__device__ inline void prepW_body(const float* W, uint16_t* WTf, int K, int NOUT, int id){
  if (id >= K*NOUT) return;
  int j    = id & 7;
  int l    = (id >> 3) & 63;
  int l15  = l & 15, quad = l >> 4;
  int rest = id >> 9;
  int KS   = K >> 5;
  int ks   = rest % KS;
  int t    = rest / KS;
  int k = ks*32 + quad*8 + j;
  int n = t*16 + l15;
  WTf[id] = f2bf(W[(size_t)k*NOUT + n]);
}

// ---------------- fused init ----------------
__global__ __launch_bounds__(256) void k_misc(
    const int* __restrict__ batch, int* __restrict__ gstart, int N, int G, int cbN,
    const float* __restrict__ W1, uint16_t* __restrict__ WT1,
    const float* __restrict__ W2, uint16_t* __restrict__ WT2,
    int* __restrict__ bcur,
    float4* __restrict__ gstats4, float4* __restrict__ embsum4)
{
  int b = blockIdx.x;
  int t = threadIdx.x;
  float4 z4 = {0.f,0.f,0.f,0.f};
  if (b < 256){
    gstats4[b*256 + t] = z4;
  } else if (b < 1280){
    embsum4[(b-256)*256 + t] = z4;
  } else if (b < 1280 + cbN){
    int i = (b-1280)*256 + t;
    if (i < N){
      int bb = batch[i];
      int bp = (i > 0) ? batch[i-1] : -1;
      for (int g = bp+1; g <= bb; g++) gstart[g] = i;
      if (i == N-1){
        for (int g = bb+1; g <= G; g++) gstart[g] = N;
      }
    }
  } else if (b == 1280 + cbN){
    for (int i = t; i < NBK_MAX; i += 256) bcur[i] = i * EB_CAP;
  } else if (b < 1280 + cbN + 1 + 32){
    prepW_body(W1, WT1, 64, 128, (b - 1280 - cbN - 1)*256 + t);
  } else {
    prepW_body(W2, WT2, 128, 256, (b - 1280 - cbN - 33)*256 + t);
  }
}

// ---------------- graph preprocessing: 128-node buckets, single-phase passA ----------------
#define PA_TILE 4096

__global__ __launch_bounds__(256) void k_passA(
    const int* __restrict__ row, const int* __restrict__ col,
    int* __restrict__ bcur, uint32_t* __restrict__ ebuf, int E)
{
  __shared__ int hist[NBK_MAX];
  __shared__ int rbase[NBK_MAX];
  int t = threadIdx.x;
  int start = blockIdx.x * PA_TILE;
  for (int i = t; i < NBK_MAX; i += 256) hist[i] = 0;
  __syncthreads();
  uint32_t myv[16]; int myb[16];
  #pragma unroll
  for (int j = 0; j < 16; j++){
    int e = start + t + j*256;
    if (e < E){
      int r = row[e], c = col[e];
      myb[j] = c >> BK_BITS;
      myv[j] = ((uint32_t)r << BK_BITS) | (uint32_t)(c & (BK_SIZE-1));
      atomicAdd(&hist[myb[j]], 1);
    } else myb[j] = -1;
  }
  __syncthreads();
  for (int i = t; i < NBK_MAX; i += 256){
    int h = hist[i];
    rbase[i] = (h > 0) ? atomicAdd(&bcur[i], h) : 0;
  }
  __syncthreads();
  for (int i = t; i < NBK_MAX; i += 256) hist[i] = 0;
  __syncthreads();
  #pragma unroll
  for (int j = 0; j < 16; j++){
    if (myb[j] >= 0){
      int pos = rbase[myb[j]] + atomicAdd(&hist[myb[j]], 1);
      ebuf[pos] = myv[j];
    }
  }
}

// passB2 (128-node buckets) + inlined bucket-prefix scan + fused x->xs conversion
__global__ __launch_bounds__(256) void k_passB2(
    const uint32_t* __restrict__ ebuf, const int* __restrict__ bcur,
    int* __restrict__ offs, float* __restrict__ dinv,
    int* __restrict__ csr,
    const float4* __restrict__ x, ushort4* __restrict__ xs,
    int N, int E, int nb)
{
  __shared__ int deg[BK_SIZE];
  __shared__ int cur[BK_SIZE];
  __shared__ int ps[BK_SIZE];
  __shared__ int red[256];
  int b = blockIdx.x;
  int base = b << BK_BITS;
  int t = threadIdx.x;
  // inline scan: s = sum of counts of buckets < b
  int partial = 0;
  for (int i = t; i < NBK_MAX; i += 256){
    int cnt = bcur[i] - i*EB_CAP;
    if (i < b) partial += cnt;
  }
  red[t] = partial;
  if (t < BK_SIZE) deg[t] = 0;
  __syncthreads();
  for (int off = 128; off > 0; off >>= 1){
    if (t < off) red[t] += red[t+off];
    __syncthreads();
  }
  int s = red[0];
  int ecnt = bcur[b] - b*EB_CAP;
  const uint32_t* eb = ebuf + (size_t)b*EB_CAP;
  for (int i = t; i < ecnt; i += 256)
    atomicAdd(&deg[eb[i] & (BK_SIZE-1u)], 1);
  __syncthreads();
  int d = (t < BK_SIZE) ? deg[t] : 0;
  if (t < BK_SIZE) ps[t] = d;
  __syncthreads();
  for (int off=1; off<BK_SIZE; off<<=1){
    int x_ = 0;
    if (t < BK_SIZE && t >= off) x_ = ps[t-off];
    __syncthreads();
    if (t < BK_SIZE && t >= off) ps[t] += x_;
    __syncthreads();
  }
  if (t < BK_SIZE){
    int o = s + ps[t] - d;
    cur[t] = o;
    int n0 = base + t;
    if (n0 < N){ offs[n0] = o; dinv[n0] = 1.0f / sqrtf((float)(d + 1)); }
  }
  if (b == nb-1 && t == 0) offs[N] = E;
  __syncthreads();
  for (int i = t; i < ecnt; i += 256){
    uint32_t v = eb[i];
    int local = v & (BK_SIZE-1u);
    int pos = atomicAdd(&cur[local], 1);
    csr[pos] = (int)(v >> BK_BITS);
  }
  for (int idx = t; idx < BK_SIZE*16; idx += 256){
    int local = idx >> 4;
    int node = base + local;
    if (node < N){
      float dd = 1.0f / sqrtf((float)(deg[local] + 1));
      int c16 = idx & 15;
      float4 v = x[(size_t)node*16 + c16];
      ushort4 o;
      o.x = f2bf(v.x*dd); o.y = f2bf(v.y*dd); o.z = f2bf(v.z*dd); o.w = f2bf(v.w*dd);
      xs[(size_t)node*16 + c16] = o;
    }
  }
}

// parallel bn finalize: one block per column, slice-parallel tree reduce
__global__ __launch_bounds__(128) void k_bnfin(const float* __restrict__ region, int F, float invCount,
                        const float* __restrict__ g, const float* __restrict__ be,
                        float* __restrict__ scale, float* __restrict__ shift){
  __shared__ float ss[128], sq[128];
  int i  = blockIdx.x;
  int sl = threadIdx.x;
  ss[sl] = region[sl*2*F + i];
  sq[sl] = region[sl*2*F + F + i];
  __syncthreads();
  for (int off = 64; off > 0; off >>= 1){
    if (sl < off){ ss[sl] += ss[sl+off]; sq[sl] += sq[sl+off]; }
    __syncthreads();
  }
  if (sl == 0){
    float mu  = ss[0] * invCount;
    float var = sq[0] * invCount - mu*mu;
    if (var < 0.f) var = 0.f;
    float rstd = 1.0f / sqrtf(var + BN_EPS);
    float sc = g[i] * rstd;
    scale[i] = sc;
    shift[i] = be[i] - mu * sc;
  }
}

// ---------------- aggregation kernels ----------------
// agg1: r6's proven 2-way split (16 nodes/block, halves combined via
// __shfl_xor(.,8)). Settled by A/B history: 1-way=61us (r4), 2-way=~48us
// (r6, best), 4-way=~65us (r8, regressed), balance permutation regresses
// (r7). Cross-iteration row pipelines spill to scratch (r2/r3, 2.2x);
// nontemporal csr refetches +24MB (r5). Do not revisit those.
__global__ __launch_bounds__(256) void k_agg1(
    const uint4* __restrict__ xs, const int* __restrict__ offs, const int* __restrict__ csr,
    const float* __restrict__ dinv, uint4* __restrict__ z, float* __restrict__ dsum, int N)
{
  int tid  = threadIdx.x;
  int sub16= tid >> 4;         // node slot within block (0..15)
  int half = (tid >> 3) & 1;   // which half of the edge list
  int lane = tid & 7;          // 16B column within the 128B row
  int node = blockIdx.x*16 + sub16;
  if (node >= N) return;
  int s0 = offs[node], e0 = offs[node+1];
  int mid = s0 + (((e0 - s0) + 1) >> 1);
  int s = half ? mid : s0;
  int e = half ? e0  : mid;
  f32x2 acc[4] = {};
  float ds = 0.f;
  auto add8 = [&](uint4 v){
    acc[0] += bfpair(v.x); acc[1] += bfpair(v.y);
    acc[2] += bfpair(v.z); acc[3] += bfpair(v.w);
  };
  int i = s;
  for (; i + 4 <= e; i += 4){
    int r0 = csr[i], r1 = csr[i+1], r2 = csr[i+2], r3 = csr[i+3];
    uint4 v0 = xs[r0*8 + lane];
    uint4 v1 = xs[r1*8 + lane];
    uint4 v2 = xs[r2*8 + lane];
    uint4 v3 = xs[r3*8 + lane];
    add8(v0); add8(v1); add8(v2); add8(v3);
    if (lane == 0) ds += dinv[r0] + dinv[r1] + dinv[r2] + dinv[r3];
  }
  for (; i < e; i++){
    int r0 = csr[i];
    add8(xs[r0*8 + lane]);
    if (lane == 0) ds += dinv[r0];
  }
  float d = dinv[node];
  if (half == 0){
    add8(xs[node*8 + lane]);           // self loop once
    if (lane == 0) ds += d;
  }
  // combine the two halves (partner lanes are tid ^ 8, same wave)
  #pragma unroll
  for (int j = 0; j < 4; j++){
    acc[j].x += __shfl_xor(acc[j].x, 8);
    acc[j].y += __shfl_xor(acc[j].y, 8);
  }
  ds += __shfl_xor(ds, 8);
  if (half == 0){
    if (lane == 0) dsum[node] = ds;
    uint4 o;
    o.x = pack2bf(acc[0].x*d, acc[0].y*d);
    o.y = pack2bf(acc[1].x*d, acc[1].y*d);
    o.z = pack2bf(acc[2].x*d, acc[2].y*d);
    o.w = pack2bf(acc[3].x*d, acc[3].y*d);
    z[(node>>4)*128 + lane*16 + (node&15)] = o;
  }
}

// agg2: gather u (fp8, 16B/lane, 8 lanes/node) -> algebraic bn1 affine -> z2
// r8's proven variant: 2-way split + SPLIT EPILOGUE (after the combine
// shuffle both halves hold the full accumulator; half 0 stores o0, half 1
// stores o1 -> full-wave epilogue instead of half-masked). Settled by A/B:
// 1-way=60.8 (r4), 2-way=62.2 (r6), 2-way+split-epi=60.7 (r8, best);
// balance permutation regresses (r7). Half-selection via per-thread-uniform
// ternaries, not runtime array indexing (scratch hazard).
__global__ __launch_bounds__(256) void k_agg2(
    const uint4* __restrict__ u, const int* __restrict__ offs, const int* __restrict__ csr,
    const float* __restrict__ dinv, const float* __restrict__ dsum,
    const float* __restrict__ sc1, const float* __restrict__ sh1,
    uint4* __restrict__ z, int N)
{
  int tid  = threadIdx.x;
  int sub16= tid >> 4;
  int half = (tid >> 3) & 1;
  int lane = tid & 7;
  int node = blockIdx.x*16 + sub16;
  if (node >= N) return;
  int s0 = offs[node], e0 = offs[node+1];
  int mid = s0 + (((e0 - s0) + 1) >> 1);
  int s = half ? mid : s0;
  int e = half ? e0  : mid;
  f32x2 acc[8] = {};
  auto add16 = [&](uint4 v){
    f32x2 p;
    p = __builtin_amdgcn_cvt_pk_f32_fp8((int)v.x, false); acc[0] += p;
    p = __builtin_amdgcn_cvt_pk_f32_fp8((int)v.x, true ); acc[1] += p;
    p = __builtin_amdgcn_cvt_pk_f32_fp8((int)v.y, false); acc[2] += p;
    p = __builtin_amdgcn_cvt_pk_f32_fp8((int)v.y, true ); acc[3] += p;
    p = __builtin_amdgcn_cvt_pk_f32_fp8((int)v.z, false); acc[4] += p;
    p = __builtin_amdgcn_cvt_pk_f32_fp8((int)v.z, true ); acc[5] += p;
    p = __builtin_amdgcn_cvt_pk_f32_fp8((int)v.w, false); acc[6] += p;
    p = __builtin_amdgcn_cvt_pk_f32_fp8((int)v.w, true ); acc[7] += p;
  };
  int i = s;
  for (; i + 4 <= e; i += 4){
    int r0 = csr[i], r1 = csr[i+1], r2 = csr[i+2], r3 = csr[i+3];
    uint4 v0 = u[r0*8 + lane];
    uint4 v1 = u[r1*8 + lane];
    uint4 v2 = u[r2*8 + lane];
    uint4 v3 = u[r3*8 + lane];
    add16(v0); add16(v1); add16(v2); add16(v3);
  }
  for (; i < e; i++) add16(u[csr[i]*8 + lane]);
  if (half == 0) add16(u[node*8 + lane]);

  // combine halves: both halves end with the full 16-feature accumulator
  #pragma unroll
  for (int j = 0; j < 8; j++){
    acc[j].x += __shfl_xor(acc[j].x, 8);
    acc[j].y += __shfl_xor(acc[j].y, 8);
  }

  float d  = dinv[node];
  float ds = dsum[node];
  // half 0 -> features [lane*16, lane*16+8) (o0 slot); half 1 -> +8 (o1 slot)
  int f0 = lane*16 + half*8;
  f32x2 a0 = half ? acc[4] : acc[0];
  f32x2 a1 = half ? acc[5] : acc[1];
  f32x2 a2 = half ? acc[6] : acc[2];
  f32x2 a3 = half ? acc[7] : acc[3];
  float4 sa = *(const float4*)(sc1 + f0);
  float4 sb = *(const float4*)(sc1 + f0 + 4);
  float4 ha = *(const float4*)(sh1 + f0);
  float4 hb = *(const float4*)(sh1 + f0 + 4);
  uint4 o;
  o.x = pack2bf(d*fmaf(sa.x, a0.x, ha.x*ds), d*fmaf(sa.y, a0.y, ha.y*ds));
  o.y = pack2bf(d*fmaf(sa.z, a1.x, ha.z*ds), d*fmaf(sa.w, a1.y, ha.w*ds));
  o.z = pack2bf(d*fmaf(sb.x, a2.x, hb.x*ds), d*fmaf(sb.y, a2.y, hb.y*ds));
  o.w = pack2bf(d*fmaf(sb.z, a3.x, hb.z*ds), d*fmaf(sb.w, a3.y, hb.w*ds));
  size_t zb = (size_t)(node>>4)*256 + (node&15);
  z[zb + (size_t)(2*lane + half)*16] = o;
}

// ---------------- MFMA node GEMM (CTILE columns per block) ----------------
// POOL: grid (mblk, NOUT/CTILE); per-column pool walk bit-identical to full-width version.
template<int K, int NOUT, int CTILE, bool POOL>
__global__ __launch_bounds__(256) void k_gemm_mfma(
    const uint16_t* __restrict__ A, const uint16_t* __restrict__ WTf,
    const float* __restrict__ bias, const int* __restrict__ batch,
    const float* __restrict__ dinv,
    uint8_t* __restrict__ u_out, float* __restrict__ embsum,
    float* __restrict__ gstats, int N)
{
  constexpr int NT = CTILE/16;
  constexpr int KS = K/32;
  constexpr int TRS8 = CTILE + 16;
  constexpr int TRSF = CTILE + 8;
  __shared__ float s_bias[CTILE];
  __shared__ int s_batch[64];
  __shared__ float s_dinv[POOL ? 1 : 64];
  __shared__ float s_sum[POOL ? 1 : CTILE];
  __shared__ float s_sq[POOL ? 1 : CTILE];
  __shared__ float s_trf[POOL ? 64*TRSF : 1];
  __shared__ uint8_t s_tr8[POOL ? 16 : 64*TRS8];
  int tid = threadIdx.x;
  int w = tid >> 6;
  int lane = tid & 63;
  int l15 = lane & 15, quad = lane >> 4;
  int m0 = blockIdx.x * 64;
  int n0 = blockIdx.y * CTILE;
  int tgbase = n0 >> 4;
  for (int i = tid; i < CTILE; i += 256) s_bias[i] = bias[n0 + i];
  if constexpr (!POOL){
    for (int i = tid; i < CTILE; i += 256){ s_sum[i]=0.f; s_sq[i]=0.f; }
    if (tid < 64) s_dinv[tid] = (m0+tid < N) ? dinv[m0+tid] : 0.f;
  }
  if (POOL && tid < 64) s_batch[tid] = (m0+tid < N) ? batch[m0+tid] : -1;
  __syncthreads();

  const uint16_t* Ag = A + (size_t)(m0/16 + w)*(16*K);

  f32x4 acc[NT];
  #pragma unroll
  for (int t=0;t<NT;t++) acc[t] = (f32x4){0.f,0.f,0.f,0.f};

  #pragma unroll
  for (int ks=0; ks<KS; ks++){
    bf16x8 af = *(const bf16x8*)(Ag + (ks*4 + quad)*128 + l15*8);
    #pragma unroll
    for (int t=0;t<NT;t++){
      bf16x8 bw = *(const bf16x8*)(WTf + (((size_t)((tgbase + t)*KS + ks)*64 + lane) << 3));
      acc[t] = __builtin_amdgcn_mfma_f32_16x16x32_bf16(af, bw, acc[t], 0, 0, 0);
    }
  }

  int rloc = w*16 + quad*4;
  if constexpr (POOL){
    #pragma unroll
    for (int t=0;t<NT;t++){
      int n = t*16 + l15;
      float bv = s_bias[n];
      #pragma unroll
      for (int r=0;r<4;r++){
        bool valid = (m0 + rloc + r) < N;
        float val = fmaxf(acc[t][r] + bv, 0.f);
        s_trf[(rloc + r)*TRSF + n] = valid ? val : 0.f;
      }
    }
    __syncthreads();
    if (tid < CTILE){
      int n = tid;
      float vs = 0.f, vq = 0.f;
      int cur = -1; float run = 0.f;
      #pragma unroll 8
      for (int row = 0; row < 64; row++){
        float v = s_trf[row*TRSF + n];
        vs += v; vq += v*v;
        int b = s_batch[row];
        if (b != cur){
          if (cur >= 0 && run != 0.f) atomicAdd(&embsum[(size_t)cur*NOUT + n0 + n], run);
          cur = b; run = v;
        } else run += v;
      }
      if (cur >= 0 && run != 0.f) atomicAdd(&embsum[(size_t)cur*NOUT + n0 + n], run);
      float* gs = gstats + (size_t)(blockIdx.x & (NSLICE-1))*(2*NOUT);
      atomicAdd(&gs[n0 + n], vs);
      atomicAdd(&gs[NOUT + n0 + n], vq);
    }
  } else {
    #pragma unroll
    for (int t=0;t<NT;t++){
      int n = t*16 + l15;
      float bv = s_bias[n];
      float vs = 0.f, vq = 0.f;
      #pragma unroll
      for (int r=0;r<4;r++){
        bool valid = (m0 + rloc + r) < N;
        float val = fmaxf(acc[t][r] + bv, 0.f);
        float o = valid ? val : 0.f;
        vs += o; vq += o*o;
        s_tr8[(rloc + r)*TRS8 + n] = f2fp8(o * s_dinv[rloc + r]);
      }
      vs += __shfl_xor(vs, 16); vs += __shfl_xor(vs, 32);
      vq += __shfl_xor(vq, 16); vq += __shfl_xor(vq, 32);
      if (quad == 0){
        atomicAdd(&s_sum[n], vs);
        atomicAdd(&s_sq[n], vq);
      }
    }
    __syncthreads();
    constexpr int CPR = CTILE/16;
    for (int i = tid; i < 64*CPR; i += 256){
      int row = i / CPR, c = i - row*CPR;
      int grow = m0 + row;
      if (grow < N)
        *(uint4*)(u_out + (size_t)grow*NOUT + n0 + c*16) = *(const uint4*)(s_tr8 + row*TRS8 + c*16);
    }
    float* gs = gstats + (size_t)(blockIdx.x & (NSLICE-1))*(2*NOUT);
    for (int i = tid; i < CTILE; i += 256){
      atomicAdd(&gs[n0 + i], s_sum[i]);
      atomicAdd(&gs[NOUT + n0 + i], s_sq[i]);
    }
  }
}

// ---------------- GEMM (head MLP, fp32), 32-row x 64-col tiles ----------------
template<int K, int NWTOT, bool CONCAT, bool AFFINE, bool EMB>
__global__ __launch_bounds__(256) void k_gemm_mlp(
    const float* __restrict__ A0, const float* __restrict__ A1,
    const float* __restrict__ W,
    const float* __restrict__ scale, const float* __restrict__ shift,
    const int* __restrict__ gstart, const float* __restrict__ esc, const float* __restrict__ esh,
    const float* __restrict__ bias,
    float* __restrict__ out, float* __restrict__ gstats, int nrows)
{
  __shared__ float As[32*69];
  __shared__ float Bs[32*64];
  __shared__ float s_sum[64], s_sq[64];
  int m0 = blockIdx.x*32;
  int n0 = blockIdx.y*64;
  int tid  = threadIdx.x;
  int tcol = tid & 15, trow = tid >> 4;
  float acc[2][4] = {};
  constexpr int NCH = (K + 31) / 32;
  for (int ch = 0; ch < NCH; ch++){
    int kc0 = ch*32;
    {
      int rr = tid >> 3; int k4 = (tid & 7) << 2;
      int row = m0 + rr;
      int kg = kc0 + k4;
      float4 v = {0.f,0.f,0.f,0.f};
      if (row < nrows){
        if constexpr (CONCAT){
          if (kg < 256){
            v = *(const float4*)(A0 + (size_t)row*256 + kg);
            if constexpr (EMB){
              int c = gstart[row+1] - gstart[row];
              if (c > 0){
                float rinv = 1.0f / (float)c;
                float4 scv = *(const float4*)(esc + kg);
                float4 shv = *(const float4*)(esh + kg);
                v.x = fmaf(v.x*rinv, scv.x, shv.x);
                v.y = fmaf(v.y*rinv, scv.y, shv.y);
                v.z = fmaf(v.z*rinv, scv.z, shv.z);
                v.w = fmaf(v.w*rinv, scv.w, shv.w);
              } else { v.x=v.y=v.z=v.w=0.f; }
            }
          }
          else if (kg < 456) v = *(const float4*)(A1 + (size_t)row*200 + (kg-256));
        } else {
          v = *(const float4*)(A0 + (size_t)row*K + kg);
        }
      }
      if constexpr (AFFINE){
        float4 scv = *(const float4*)(scale + kg);
        float4 shv = *(const float4*)(shift + kg);
        v.x = fmaf(v.x, scv.x, shv.x);
        v.y = fmaf(v.y, scv.y, shv.y);
        v.z = fmaf(v.z, scv.z, shv.z);
        v.w = fmaf(v.w, scv.w, shv.w);
      }
      As[(k4+0)*69 + rr] = v.x;
      As[(k4+1)*69 + rr] = v.y;
      As[(k4+2)*69 + rr] = v.z;
      As[(k4+3)*69 + rr] = v.w;
    }
    #pragma unroll
    for (int j = 0; j < 2; j++){
      int fid = tid + j*256;
      int kk = fid >> 4; int c4 = (fid & 15) << 2;
      int kg = kc0 + kk;
      float4 v = {0.f,0.f,0.f,0.f};
      if (kg < K) v = *(const float4*)(W + (size_t)kg*NWTOT + n0 + c4);
      *(float4*)(Bs + kk*64 + c4) = v;
    }
    __syncthreads();
    #pragma unroll
    for (int kk = 0; kk < 32; kk++){
      float4 b = *(const float4*)(Bs + kk*64 + tcol*4);
      float a0 = As[kk*69 + trow*2];
      float a1 = As[kk*69 + trow*2 + 1];
      acc[0][0] = fmaf(a0, b.x, acc[0][0]);
      acc[0][1] = fmaf(a0, b.y, acc[0][1]);
      acc[0][2] = fmaf(a0, b.z, acc[0][2]);
      acc[0][3] = fmaf(a0, b.w, acc[0][3]);
      acc[1][0] = fmaf(a1, b.x, acc[1][0]);
      acc[1][1] = fmaf(a1, b.y, acc[1][1]);
      acc[1][2] = fmaf(a1, b.z, acc[1][2]);
      acc[1][3] = fmaf(a1, b.w, acc[1][3]);
    }
    __syncthreads();
  }
  if (tid < 64){ s_sum[tid] = 0.f; s_sq[tid] = 0.f; }
  __syncthreads();
  float4 bv = *(const float4*)(bias + n0 + tcol*4);
  float psum[4] = {0,0,0,0}, psq[4] = {0,0,0,0};
  #pragma unroll
  for (int r = 0; r < 2; r++){
    int row = m0 + trow*2 + r;
    if (row < nrows){
      float4 o;
      o.x = fmaxf(acc[r][0] + bv.x, 0.f);
      o.y = fmaxf(acc[r][1] + bv.y, 0.f);
      o.z = fmaxf(acc[r][2] + bv.z, 0.f);
      o.w = fmaxf(acc[r][3] + bv.w, 0.f);
      *(float4*)(out + (size_t)row*NWTOT + n0 + tcol*4) = o;
      psum[0] += o.x; psq[0] += o.x*o.x;
      psum[1] += o.y; psq[1] += o.y*o.y;
      psum[2] += o.z; psq[2] += o.z*o.z;
      psum[3] += o.w; psq[3] += o.w*o.w;
    }
  }
  #pragma unroll
  for (int c = 0; c < 4; c++){
    psum[c] += __shfl_xor(psum[c], 16); psum[c] += __shfl_xor(psum[c], 32);
    psq[c]  += __shfl_xor(psq[c], 16);  psq[c]  += __shfl_xor(psq[c], 32);
  }
  if ((tid & 48) == 0){
    int f0 = tcol*4;
    atomicAdd(&s_sum[f0+0], psum[0]); atomicAdd(&s_sq[f0+0], psq[0]);
    atomicAdd(&s_sum[f0+1], psum[1]); atomicAdd(&s_sq[f0+1], psq[1]);
    atomicAdd(&s_sum[f0+2], psum[2]); atomicAdd(&s_sq[f0+2], psq[2]);
    atomicAdd(&s_sum[f0+3], psum[3]); atomicAdd(&s_sq[f0+3], psq[3]);
  }
  __syncthreads();
  float* gs = gstats + (size_t)(blockIdx.x & (NSLICE-1))*(2*NWTOT);
  if (tid < 64){
    atomicAdd(&gs[n0 + tid], s_sum[tid]);
    atomicAdd(&gs[NWTOT + n0 + tid], s_sq[tid]);
  }
}

// ---------------- final ----------------
__global__ __launch_bounds__(256) void k_final(
    const float* __restrict__ a2, const float* __restrict__ sc, const float* __restrict__ sh,
    const float* __restrict__ w, const float* __restrict__ b, float* __restrict__ out, int G)
{
  int gid  = blockIdx.x*blockDim.x + threadIdx.x;
  int wid  = gid >> 6;
  int lane = gid & 63;
  if (wid >= G) return;
  float2 v = ((const float2*)(a2 + (size_t)wid*128))[lane];
  int k = lane*2;
  float s = fmaf(v.x, sc[k], sh[k]) * w[k] + fmaf(v.y, sc[k+1], sh[k+1]) * w[k+1];
  #pragma unroll
  for (int o = 32; o > 0; o >>= 1) s += __shfl_down(s, o, 64);
  if (lane == 0) out[wid] = s + b[0];
}

// ---------------- launcher ----------------
extern "C" void kernel_launch(void* const* d_in, const int* in_sizes, int n_in,
                              void* d_out, int out_size, void* d_ws, size_t ws_size,
                              hipStream_t stream)
{
  (void)n_in; (void)out_size; (void)ws_size;
  const float* x    = (const float*)d_in[0];
  const int*   ei   = (const int*)d_in[1];
  const int*   batch= (const int*)d_in[2];
  const float* rdk  = (const float*)d_in[3];
  const float* W1   = (const float*)d_in[4];
  const float* b1   = (const float*)d_in[5];
  const float* g1   = (const float*)d_in[6];
  const float* be1  = (const float*)d_in[7];
  const float* W2   = (const float*)d_in[8];
  const float* b2   = (const float*)d_in[9];
  const float* g2   = (const float*)d_in[10];
  const float* be2  = (const float*)d_in[11];
  const float* mW1  = (const float*)d_in[12];
  const float* mb1  = (const float*)d_in[13];
  const float* mg1  = (const float*)d_in[14];
  const float* mbe1 = (const float*)d_in[15];
  const float* mW2  = (const float*)d_in[16];
  const float* mb2  = (const float*)d_in[17];
  const float* mg2  = (const float*)d_in[18];
  const float* mbe2 = (const float*)d_in[19];
  const float* mW3  = (const float*)d_in[20];
  const float* mb3  = (const float*)d_in[21];

  const int N = in_sizes[0] / 64;
  const int E = in_sizes[1] / 2;
  const int G = in_sizes[3] / 200;
  const int* erow = ei;
  const int* ecol = ei + E;
  const int nb = (N + BK_SIZE - 1) >> BK_BITS;

  size_t off = 0;
  auto alloc = [&](size_t bytes)->char*{
    char* p = (char*)d_ws + off;
    off += (bytes + 255) & ~(size_t)255;
    return p;
  };
  int*   offs   = (int*)  alloc(((size_t)N+1)*4);
  int*   csr    = (int*)  alloc((size_t)E*4);
  uint32_t* ebuf= (uint32_t*)alloc((size_t)NBK_MAX*EB_CAP*4);
  int*   bcur   = (int*)  alloc(NBK_MAX*4);
  float* dinv   = (float*)alloc((size_t)N*4);
  float* dsum   = (float*)alloc((size_t)N*4);
  uint16_t* xs  = (uint16_t*)alloc((size_t)N*64*2);
  uint16_t* z1  = (uint16_t*)alloc(((size_t)N+16)*64*2);
  uint8_t*  u   = (uint8_t*)alloc((size_t)N*128);
  uint16_t* z2  = (uint16_t*)alloc(((size_t)N+16)*128*2);
  uint16_t* WT1 = (uint16_t*)alloc((size_t)128*64*2);
  uint16_t* WT2 = (uint16_t*)alloc((size_t)256*128*2);
  float* embsum = (float*)alloc((size_t)G*256*4);
  int*   gstart = (int*)  alloc(((size_t)G+1)*4);
  float* a1     = (float*)alloc((size_t)G*256*4);
  float* a2     = (float*)alloc((size_t)G*128*4);
  float* gstats = (float*)alloc((size_t)4*NSLICE*2*256*4);
  float* scsh   = (float*)alloc((size_t)4*2*256*4);

  float* gs0 = gstats;
  float* gs1 = gstats + NSLICE*2*256;
  float* gs2 = gstats + 2*NSLICE*2*256;
  float* gs3 = gstats + 3*NSLICE*2*256;
  float* sc1 = scsh;        float* sh1 = scsh + 256;
  float* sc2 = scsh + 512;  float* sh2 = scsh + 768;
  float* sc3 = scsh + 1024; float* sh3 = scsh + 1280;
  float* sc4 = scsh + 1536; float* sh4 = scsh + 1792;

  int cbN   = (N + 255) / 256;
  int mblk  = (N + 63) / 64;
  int gblk32= (G + 31) / 32;
  int ablk  = (E + PA_TILE - 1) / PA_TILE;

  k_misc<<<1280 + cbN + 1 + 32 + 128, 256, 0, stream>>>(
      batch, gstart, N, G, cbN, W1, WT1, W2, WT2, bcur,
      (float4*)gstats, (float4*)embsum);

  k_passA<<<ablk,256,0,stream>>>(erow, ecol, bcur, ebuf, E);
  k_passB2<<<nb,256,0,stream>>>(ebuf, bcur, offs, dinv, csr, (const float4*)x, (ushort4*)xs, N, E, nb);

  k_agg1<<<(N+15)/16,256,0,stream>>>((const uint4*)xs, offs, csr, dinv, (uint4*)z1, dsum, N);
  k_gemm_mfma<64,128,128,false><<<dim3(mblk,1),256,0,stream>>>(z1, WT1, b1, nullptr, dinv, u, nullptr, gs0, N);
  k_bnfin<<<128,128,0,stream>>>(gs0, 128, 1.0f/(float)N, g1, be1, sc1, sh1);

  k_agg2<<<(N+15)/16,256,0,stream>>>((const uint4*)u, offs, csr, dinv, dsum, sc1, sh1, (uint4*)z2, N);
  k_gemm_mfma<128,256,128,true><<<dim3(mblk,2),256,0,stream>>>(z2, WT2, b2, batch, nullptr, nullptr, embsum, gs1, N);
  k_bnfin<<<256,128,0,stream>>>(gs1, 256, 1.0f/(float)N, g2, be2, sc2, sh2);

  k_gemm_mlp<456,256,true,false,true><<<dim3(gblk32,4),256,0,stream>>>(embsum, rdk, mW1, nullptr, nullptr, gstart, sc2, sh2, mb1, a1, gs2, G);
  k_bnfin<<<256,128,0,stream>>>(gs2, 256, 1.0f/(float)G, mg1, mbe1, sc3, sh3);
  k_gemm_mlp<256,128,false,true,false><<<dim3(gblk32,2),256,0,stream>>>(a1, nullptr, mW2, sc3, sh3, nullptr, nullptr, nullptr, mb2, a2, gs3, G);
  k_bnfin<<<128,128,0,stream>>>(gs3, 128, 1.0f/(float)G, mg2, mbe2, sc4, sh4);
  k_final<<<(G+3)/4,256,0,stream>>>(a2, sc4, sh4, mW3, mb3, (float*)d_out, G);
}

// Round 10
// 423.168 us; speedup vs baseline: 1.0587x; 1.0208x over previous
//
#include <hip/hip_runtime.h>
#include <cstdint>
#include <cstddef>

#define BN_EPS 1e-5f
#define NSLICE 128
#define BK_BITS 7
#define BK_SIZE 128
#define NBK_MAX 1024
#define EB_CAP 5120

typedef __attribute__((ext_vector_type(8))) __bf16 bf16x8;
typedef __attribute__((ext_vector_type(4))) float f32x4;
typedef __attribute__((ext_vector_type(2))) float f32x2;

// ---------------- helpers ----------------

__device__ inline uint16_t f2bf(float f){
  union {float f; uint32_t u;} v; v.f = f;
  uint32_t u = v.u;
  return (uint16_t)((u + 0x7FFFu + ((u >> 16) & 1u)) >> 16);
}

__device__ inline uint32_t pack2bf(float a, float b){
  return (uint32_t)f2bf(a) | ((uint32_t)f2bf(b) << 16);
}

__device__ inline void bf2f2(uint32_t w, float& a, float& b){
  union {uint32_t u; float f;} ua, ub;
  ua.u = w << 16; ub.u = w & 0xFFFF0000u;
  a = ua.f; b = ub.f;
}

// unpack a bf16 pair word into a packed f32x2 (low half, high half)
__device__ inline f32x2 bfpair(uint32_t w){
  union {uint32_t u; float f;} ua, ub;
  ua.u = w << 16; ub.u = w & 0xFFFF0000u;
  return (f32x2){ua.f, ub.f};
}

__device__ inline uint8_t f2fp8(float v){
  uint32_t t = (uint32_t)__builtin_amdgcn_cvt_pk_fp8_f32(v, v, 0, false);
  return (uint8_t)(t & 0xFF);
}

__device__ inline void prepW_body(const float* W, uint16_t* WTf, int K, int NOUT, int id){
  if (id >= K*NOUT) return;
  int j    = id & 7;
  int l    = (id >> 3) & 63;
  int l15  = l & 15, quad = l >> 4;
  int rest = id >> 9;
  int KS   = K >> 5;
  int ks   = rest % KS;
  int t    = rest / KS;
  int k = ks*32 + quad*8 + j;
  int n = t*16 + l15;
  WTf[id] = f2bf(W[(size_t)k*NOUT + n]);
}

// ---------------- fused init ----------------
__global__ __launch_bounds__(256) void k_misc(
    const int* __restrict__ batch, int* __restrict__ gstart, int N, int G, int cbN,
    const float* __restrict__ W1, uint16_t* __restrict__ WT1,
    const float* __restrict__ W2, uint16_t* __restrict__ WT2,
    int* __restrict__ bcur,
    float4* __restrict__ gstats4, float4* __restrict__ embsum4)
{
  int b = blockIdx.x;
  int t = threadIdx.x;
  float4 z4 = {0.f,0.f,0.f,0.f};
  if (b < 256){
    gstats4[b*256 + t] = z4;
  } else if (b < 1280){
    embsum4[(b-256)*256 + t] = z4;
  } else if (b < 1280 + cbN){
    int i = (b-1280)*256 + t;
    if (i < N){
      int bb = batch[i];
      int bp = (i > 0) ? batch[i-1] : -1;
      for (int g = bp+1; g <= bb; g++) gstart[g] = i;
      if (i == N-1){
        for (int g = bb+1; g <= G; g++) gstart[g] = N;
      }
    }
  } else if (b == 1280 + cbN){
    for (int i = t; i < NBK_MAX; i += 256) bcur[i] = i * EB_CAP;
  } else if (b < 1280 + cbN + 1 + 32){
    prepW_body(W1, WT1, 64, 128, (b - 1280 - cbN - 1)*256 + t);
  } else {
    prepW_body(W2, WT2, 128, 256, (b - 1280 - cbN - 33)*256 + t);
  }
}

// ---------------- graph preprocessing: 128-node buckets, single-phase passA ----------------
#define PA_TILE 4096

__global__ __launch_bounds__(256) void k_passA(
    const int* __restrict__ row, const int* __restrict__ col,
    int* __restrict__ bcur, uint32_t* __restrict__ ebuf, int E)
{
  __shared__ int hist[NBK_MAX];
  __shared__ int rbase[NBK_MAX];
  int t = threadIdx.x;
  int start = blockIdx.x * PA_TILE;
  for (int i = t; i < NBK_MAX; i += 256) hist[i] = 0;
  __syncthreads();
  uint32_t myv[16]; int myb[16];
  #pragma unroll
  for (int j = 0; j < 16; j++){
    int e = start + t + j*256;
    if (e < E){
      int r = row[e], c = col[e];
      myb[j] = c >> BK_BITS;
      myv[j] = ((uint32_t)r << BK_BITS) | (uint32_t)(c & (BK_SIZE-1));
      atomicAdd(&hist[myb[j]], 1);
    } else myb[j] = -1;
  }
  __syncthreads();
  for (int i = t; i < NBK_MAX; i += 256){
    int h = hist[i];
    rbase[i] = (h > 0) ? atomicAdd(&bcur[i], h) : 0;
  }
  __syncthreads();
  for (int i = t; i < NBK_MAX; i += 256) hist[i] = 0;
  __syncthreads();
  #pragma unroll
  for (int j = 0; j < 16; j++){
    if (myb[j] >= 0){
      int pos = rbase[myb[j]] + atomicAdd(&hist[myb[j]], 1);
      ebuf[pos] = myv[j];
    }
  }
}

// passB2 (128-node buckets) + inlined bucket-prefix scan + fused x->xs conversion
__global__ __launch_bounds__(256) void k_passB2(
    const uint32_t* __restrict__ ebuf, const int* __restrict__ bcur,
    int* __restrict__ offs, float* __restrict__ dinv,
    int* __restrict__ csr,
    const float4* __restrict__ x, ushort4* __restrict__ xs,
    int N, int E, int nb)
{
  __shared__ int deg[BK_SIZE];
  __shared__ int cur[BK_SIZE];
  __shared__ int ps[BK_SIZE];
  __shared__ int red[256];
  int b = blockIdx.x;
  int base = b << BK_BITS;
  int t = threadIdx.x;
  // inline scan: s = sum of counts of buckets < b
  int partial = 0;
  for (int i = t; i < NBK_MAX; i += 256){
    int cnt = bcur[i] - i*EB_CAP;
    if (i < b) partial += cnt;
  }
  red[t] = partial;
  if (t < BK_SIZE) deg[t] = 0;
  __syncthreads();
  for (int off = 128; off > 0; off >>= 1){
    if (t < off) red[t] += red[t+off];
    __syncthreads();
  }
  int s = red[0];
  int ecnt = bcur[b] - b*EB_CAP;
  const uint32_t* eb = ebuf + (size_t)b*EB_CAP;
  for (int i = t; i < ecnt; i += 256)
    atomicAdd(&deg[eb[i] & (BK_SIZE-1u)], 1);
  __syncthreads();
  int d = (t < BK_SIZE) ? deg[t] : 0;
  if (t < BK_SIZE) ps[t] = d;
  __syncthreads();
  for (int off=1; off<BK_SIZE; off<<=1){
    int x_ = 0;
    if (t < BK_SIZE && t >= off) x_ = ps[t-off];
    __syncthreads();
    if (t < BK_SIZE && t >= off) ps[t] += x_;
    __syncthreads();
  }
  if (t < BK_SIZE){
    int o = s + ps[t] - d;
    cur[t] = o;
    int n0 = base + t;
    if (n0 < N){ offs[n0] = o; dinv[n0] = 1.0f / sqrtf((float)(d + 1)); }
  }
  if (b == nb-1 && t == 0) offs[N] = E;
  __syncthreads();
  for (int i = t; i < ecnt; i += 256){
    uint32_t v = eb[i];
    int local = v & (BK_SIZE-1u);
    int pos = atomicAdd(&cur[local], 1);
    csr[pos] = (int)(v >> BK_BITS);
  }
  for (int idx = t; idx < BK_SIZE*16; idx += 256){
    int local = idx >> 4;
    int node = base + local;
    if (node < N){
      float dd = 1.0f / sqrtf((float)(deg[local] + 1));
      int c16 = idx & 15;
      float4 v = x[(size_t)node*16 + c16];
      ushort4 o;
      o.x = f2bf(v.x*dd); o.y = f2bf(v.y*dd); o.z = f2bf(v.z*dd); o.w = f2bf(v.w*dd);
      xs[(size_t)node*16 + c16] = o;
    }
  }
}

// parallel bn finalize: one block per column, slice-parallel tree reduce
__global__ __launch_bounds__(128) void k_bnfin(const float* __restrict__ region, int F, float invCount,
                        const float* __restrict__ g, const float* __restrict__ be,
                        float* __restrict__ scale, float* __restrict__ shift){
  __shared__ float ss[128], sq[128];
  int i  = blockIdx.x;
  int sl = threadIdx.x;
  ss[sl] = region[sl*2*F + i];
  sq[sl] = region[sl*2*F + F + i];
  __syncthreads();
  for (int off = 64; off > 0; off >>= 1){
    if (sl < off){ ss[sl] += ss[sl+off]; sq[sl] += sq[sl+off]; }
    __syncthreads();
  }
  if (sl == 0){
    float mu  = ss[0] * invCount;
    float var = sq[0] * invCount - mu*mu;
    if (var < 0.f) var = 0.f;
    float rstd = 1.0f / sqrtf(var + BN_EPS);
    float sc = g[i] * rstd;
    scale[i] = sc;
    shift[i] = be[i] - mu * sc;
  }
}

// ---------------- aggregation kernels ----------------
// agg1: r6's proven 2-way split (16 nodes/block, halves combined via
// __shfl_xor(.,8)). Settled by A/B history: 1-way=61us (r4), 2-way=~48us
// (r6, best), 4-way=~65us (r8, regressed), balance permutation regresses
// (r7). Cross-iteration row pipelines spill to scratch (r2/r3, 2.2x);
// nontemporal csr refetches +24MB (r5). Do not revisit those.
__global__ __launch_bounds__(256) void k_agg1(
    const uint4* __restrict__ xs, const int* __restrict__ offs, const int* __restrict__ csr,
    const float* __restrict__ dinv, uint4* __restrict__ z, float* __restrict__ dsum, int N)
{
  int tid  = threadIdx.x;
  int sub16= tid >> 4;         // node slot within block (0..15)
  int half = (tid >> 3) & 1;   // which half of the edge list
  int lane = tid & 7;          // 16B column within the 128B row
  int node = blockIdx.x*16 + sub16;
  if (node >= N) return;
  int s0 = offs[node], e0 = offs[node+1];
  int mid = s0 + (((e0 - s0) + 1) >> 1);
  int s = half ? mid : s0;
  int e = half ? e0  : mid;
  f32x2 acc[4] = {};
  float ds = 0.f;
  auto add8 = [&](uint4 v){
    acc[0] += bfpair(v.x); acc[1] += bfpair(v.y);
    acc[2] += bfpair(v.z); acc[3] += bfpair(v.w);
  };
  int i = s;
  for (; i + 4 <= e; i += 4){
    int r0 = csr[i], r1 = csr[i+1], r2 = csr[i+2], r3 = csr[i+3];
    uint4 v0 = xs[r0*8 + lane];
    uint4 v1 = xs[r1*8 + lane];
    uint4 v2 = xs[r2*8 + lane];
    uint4 v3 = xs[r3*8 + lane];
    add8(v0); add8(v1); add8(v2); add8(v3);
    if (lane == 0) ds += dinv[r0] + dinv[r1] + dinv[r2] + dinv[r3];
  }
  for (; i < e; i++){
    int r0 = csr[i];
    add8(xs[r0*8 + lane]);
    if (lane == 0) ds += dinv[r0];
  }
  float d = dinv[node];
  if (half == 0){
    add8(xs[node*8 + lane]);           // self loop once
    if (lane == 0) ds += d;
  }
  // combine the two halves (partner lanes are tid ^ 8, same wave)
  #pragma unroll
  for (int j = 0; j < 4; j++){
    acc[j].x += __shfl_xor(acc[j].x, 8);
    acc[j].y += __shfl_xor(acc[j].y, 8);
  }
  ds += __shfl_xor(ds, 8);
  if (half == 0){
    if (lane == 0) dsum[node] = ds;
    uint4 o;
    o.x = pack2bf(acc[0].x*d, acc[0].y*d);
    o.y = pack2bf(acc[1].x*d, acc[1].y*d);
    o.z = pack2bf(acc[2].x*d, acc[2].y*d);
    o.w = pack2bf(acc[3].x*d, acc[3].y*d);
    z[(node>>4)*128 + lane*16 + (node&15)] = o;
  }
}

// agg2: gather u (fp8, 16B/lane, 8 lanes/node) -> algebraic bn1 affine -> z2
// r8's proven variant: 2-way split + SPLIT EPILOGUE (after the combine
// shuffle both halves hold the full accumulator; half 0 stores o0, half 1
// stores o1 -> full-wave epilogue instead of half-masked). Settled by A/B:
// 1-way=60.8 (r4), 2-way=62.2 (r6), 2-way+split-epi=60.7 (r8, best);
// balance permutation regresses (r7). Half-selection via per-thread-uniform
// ternaries, not runtime array indexing (scratch hazard).
__global__ __launch_bounds__(256) void k_agg2(
    const uint4* __restrict__ u, const int* __restrict__ offs, const int* __restrict__ csr,
    const float* __restrict__ dinv, const float* __restrict__ dsum,
    const float* __restrict__ sc1, const float* __restrict__ sh1,
    uint4* __restrict__ z, int N)
{
  int tid  = threadIdx.x;
  int sub16= tid >> 4;
  int half = (tid >> 3) & 1;
  int lane = tid & 7;
  int node = blockIdx.x*16 + sub16;
  if (node >= N) return;
  int s0 = offs[node], e0 = offs[node+1];
  int mid = s0 + (((e0 - s0) + 1) >> 1);
  int s = half ? mid : s0;
  int e = half ? e0  : mid;
  f32x2 acc[8] = {};
  auto add16 = [&](uint4 v){
    f32x2 p;
    p = __builtin_amdgcn_cvt_pk_f32_fp8((int)v.x, false); acc[0] += p;
    p = __builtin_amdgcn_cvt_pk_f32_fp8((int)v.x, true ); acc[1] += p;
    p = __builtin_amdgcn_cvt_pk_f32_fp8((int)v.y, false); acc[2] += p;
    p = __builtin_amdgcn_cvt_pk_f32_fp8((int)v.y, true ); acc[3] += p;
    p = __builtin_amdgcn_cvt_pk_f32_fp8((int)v.z, false); acc[4] += p;
    p = __builtin_amdgcn_cvt_pk_f32_fp8((int)v.z, true ); acc[5] += p;
    p = __builtin_amdgcn_cvt_pk_f32_fp8((int)v.w, false); acc[6] += p;
    p = __builtin_amdgcn_cvt_pk_f32_fp8((int)v.w, true ); acc[7] += p;
  };
  int i = s;
  for (; i + 4 <= e; i += 4){
    int r0 = csr[i], r1 = csr[i+1], r2 = csr[i+2], r3 = csr[i+3];
    uint4 v0 = u[r0*8 + lane];
    uint4 v1 = u[r1*8 + lane];
    uint4 v2 = u[r2*8 + lane];
    uint4 v3 = u[r3*8 + lane];
    add16(v0); add16(v1); add16(v2); add16(v3);
  }
  for (; i < e; i++) add16(u[csr[i]*8 + lane]);
  if (half == 0) add16(u[node*8 + lane]);

  // combine halves: both halves end with the full 16-feature accumulator
  #pragma unroll
  for (int j = 0; j < 8; j++){
    acc[j].x += __shfl_xor(acc[j].x, 8);
    acc[j].y += __shfl_xor(acc[j].y, 8);
  }

  float d  = dinv[node];
  float ds = dsum[node];
  // half 0 -> features [lane*16, lane*16+8) (o0 slot); half 1 -> +8 (o1 slot)
  int f0 = lane*16 + half*8;
  f32x2 a0 = half ? acc[4] : acc[0];
  f32x2 a1 = half ? acc[5] : acc[1];
  f32x2 a2 = half ? acc[6] : acc[2];
  f32x2 a3 = half ? acc[7] : acc[3];
  float4 sa = *(const float4*)(sc1 + f0);
  float4 sb = *(const float4*)(sc1 + f0 + 4);
  float4 ha = *(const float4*)(sh1 + f0);
  float4 hb = *(const float4*)(sh1 + f0 + 4);
  uint4 o;
  o.x = pack2bf(d*fmaf(sa.x, a0.x, ha.x*ds), d*fmaf(sa.y, a0.y, ha.y*ds));
  o.y = pack2bf(d*fmaf(sa.z, a1.x, ha.z*ds), d*fmaf(sa.w, a1.y, ha.w*ds));
  o.z = pack2bf(d*fmaf(sb.x, a2.x, hb.x*ds), d*fmaf(sb.y, a2.y, hb.y*ds));
  o.w = pack2bf(d*fmaf(sb.z, a3.x, hb.z*ds), d*fmaf(sb.w, a3.y, hb.w*ds));
  size_t zb = (size_t)(node>>4)*256 + (node&15);
  z[zb + (size_t)(2*lane + half)*16] = o;
}

// ---------------- MFMA node GEMM (CTILE columns per block) ----------------
// POOL: grid (mblk, NOUT/CTILE). r10: pool walk parallelized 2x — all 256
// threads participate as (column, row-half); each walks 32 rows instead of
// 128 threads walking 64. Batch runs crossing the half boundary emit two
// additive atomicAdds to the same embsum cell (identical sum); vs/vq split
// into two additive atomics per column. Halves the serial LDS-walk chain
// that the 32-MFMA main loop cannot hide.
template<int K, int NOUT, int CTILE, bool POOL>
__global__ __launch_bounds__(256) void k_gemm_mfma(
    const uint16_t* __restrict__ A, const uint16_t* __restrict__ WTf,
    const float* __restrict__ bias, const int* __restrict__ batch,
    const float* __restrict__ dinv,
    uint8_t* __restrict__ u_out, float* __restrict__ embsum,
    float* __restrict__ gstats, int N)
{
  constexpr int NT = CTILE/16;
  constexpr int KS = K/32;
  constexpr int TRS8 = CTILE + 16;
  constexpr int TRSF = CTILE + 8;
  __shared__ float s_bias[CTILE];
  __shared__ int s_batch[64];
  __shared__ float s_dinv[POOL ? 1 : 64];
  __shared__ float s_sum[POOL ? 1 : CTILE];
  __shared__ float s_sq[POOL ? 1 : CTILE];
  __shared__ float s_trf[POOL ? 64*TRSF : 1];
  __shared__ uint8_t s_tr8[POOL ? 16 : 64*TRS8];
  int tid = threadIdx.x;
  int w = tid >> 6;
  int lane = tid & 63;
  int l15 = lane & 15, quad = lane >> 4;
  int m0 = blockIdx.x * 64;
  int n0 = blockIdx.y * CTILE;
  int tgbase = n0 >> 4;
  for (int i = tid; i < CTILE; i += 256) s_bias[i] = bias[n0 + i];
  if constexpr (!POOL){
    for (int i = tid; i < CTILE; i += 256){ s_sum[i]=0.f; s_sq[i]=0.f; }
    if (tid < 64) s_dinv[tid] = (m0+tid < N) ? dinv[m0+tid] : 0.f;
  }
  if (POOL && tid < 64) s_batch[tid] = (m0+tid < N) ? batch[m0+tid] : -1;
  __syncthreads();

  const uint16_t* Ag = A + (size_t)(m0/16 + w)*(16*K);

  f32x4 acc[NT];
  #pragma unroll
  for (int t=0;t<NT;t++) acc[t] = (f32x4){0.f,0.f,0.f,0.f};

  #pragma unroll
  for (int ks=0; ks<KS; ks++){
    bf16x8 af = *(const bf16x8*)(Ag + (ks*4 + quad)*128 + l15*8);
    #pragma unroll
    for (int t=0;t<NT;t++){
      bf16x8 bw = *(const bf16x8*)(WTf + (((size_t)((tgbase + t)*KS + ks)*64 + lane) << 3));
      acc[t] = __builtin_amdgcn_mfma_f32_16x16x32_bf16(af, bw, acc[t], 0, 0, 0);
    }
  }

  int rloc = w*16 + quad*4;
  if constexpr (POOL){
    #pragma unroll
    for (int t=0;t<NT;t++){
      int n = t*16 + l15;
      float bv = s_bias[n];
      #pragma unroll
      for (int r=0;r<4;r++){
        bool valid = (m0 + rloc + r) < N;
        float val = fmaxf(acc[t][r] + bv, 0.f);
        s_trf[(rloc + r)*TRSF + n] = valid ? val : 0.f;
      }
    }
    __syncthreads();
    {
      constexpr int NSPLIT = 256/CTILE;      // 2 for CTILE=128
      constexpr int RPW = 64/NSPLIT;         // 32 rows per walker
      int n  = tid & (CTILE-1);
      int rh = tid / CTILE;                  // row-half index
      int r0 = rh * RPW;
      float vs = 0.f, vq = 0.f;
      int cur = -1; float run = 0.f;
      #pragma unroll 8
      for (int row = r0; row < r0 + RPW; row++){
        float v = s_trf[row*TRSF + n];
        vs += v; vq += v*v;
        int b = s_batch[row];
        if (b != cur){
          if (cur >= 0 && run != 0.f) atomicAdd(&embsum[(size_t)cur*NOUT + n0 + n], run);
          cur = b; run = v;
        } else run += v;
      }
      if (cur >= 0 && run != 0.f) atomicAdd(&embsum[(size_t)cur*NOUT + n0 + n], run);
      float* gs = gstats + (size_t)(blockIdx.x & (NSLICE-1))*(2*NOUT);
      if (vs != 0.f || vq != 0.f){
        atomicAdd(&gs[n0 + n], vs);
        atomicAdd(&gs[NOUT + n0 + n], vq);
      }
    }
  } else {
    #pragma unroll
    for (int t=0;t<NT;t++){
      int n = t*16 + l15;
      float bv = s_bias[n];
      float vs = 0.f, vq = 0.f;
      #pragma unroll
      for (int r=0;r<4;r++){
        bool valid = (m0 + rloc + r) < N;
        float val = fmaxf(acc[t][r] + bv, 0.f);
        float o = valid ? val : 0.f;
        vs += o; vq += o*o;
        s_tr8[(rloc + r)*TRS8 + n] = f2fp8(o * s_dinv[rloc + r]);
      }
      vs += __shfl_xor(vs, 16); vs += __shfl_xor(vs, 32);
      vq += __shfl_xor(vq, 16); vq += __shfl_xor(vq, 32);
      if (quad == 0){
        atomicAdd(&s_sum[n], vs);
        atomicAdd(&s_sq[n], vq);
      }
    }
    __syncthreads();
    constexpr int CPR = CTILE/16;
    for (int i = tid; i < 64*CPR; i += 256){
      int row = i / CPR, c = i - row*CPR;
      int grow = m0 + row;
      if (grow < N)
        *(uint4*)(u_out + (size_t)grow*NOUT + n0 + c*16) = *(const uint4*)(s_tr8 + row*TRS8 + c*16);
    }
    float* gs = gstats + (size_t)(blockIdx.x & (NSLICE-1))*(2*NOUT);
    for (int i = tid; i < CTILE; i += 256){
      atomicAdd(&gs[n0 + i], s_sum[i]);
      atomicAdd(&gs[NOUT + n0 + i], s_sq[i]);
    }
  }
}

// ---------------- GEMM (head MLP, fp32), 32-row x 64-col tiles ----------------
template<int K, int NWTOT, bool CONCAT, bool AFFINE, bool EMB>
__global__ __launch_bounds__(256) void k_gemm_mlp(
    const float* __restrict__ A0, const float* __restrict__ A1,
    const float* __restrict__ W,
    const float* __restrict__ scale, const float* __restrict__ shift,
    const int* __restrict__ gstart, const float* __restrict__ esc, const float* __restrict__ esh,
    const float* __restrict__ bias,
    float* __restrict__ out, float* __restrict__ gstats, int nrows)
{
  __shared__ float As[32*69];
  __shared__ float Bs[32*64];
  __shared__ float s_sum[64], s_sq[64];
  int m0 = blockIdx.x*32;
  int n0 = blockIdx.y*64;
  int tid  = threadIdx.x;
  int tcol = tid & 15, trow = tid >> 4;
  float acc[2][4] = {};
  constexpr int NCH = (K + 31) / 32;
  for (int ch = 0; ch < NCH; ch++){
    int kc0 = ch*32;
    {
      int rr = tid >> 3; int k4 = (tid & 7) << 2;
      int row = m0 + rr;
      int kg = kc0 + k4;
      float4 v = {0.f,0.f,0.f,0.f};
      if (row < nrows){
        if constexpr (CONCAT){
          if (kg < 256){
            v = *(const float4*)(A0 + (size_t)row*256 + kg);
            if constexpr (EMB){
              int c = gstart[row+1] - gstart[row];
              if (c > 0){
                float rinv = 1.0f / (float)c;
                float4 scv = *(const float4*)(esc + kg);
                float4 shv = *(const float4*)(esh + kg);
                v.x = fmaf(v.x*rinv, scv.x, shv.x);
                v.y = fmaf(v.y*rinv, scv.y, shv.y);
                v.z = fmaf(v.z*rinv, scv.z, shv.z);
                v.w = fmaf(v.w*rinv, scv.w, shv.w);
              } else { v.x=v.y=v.z=v.w=0.f; }
            }
          }
          else if (kg < 456) v = *(const float4*)(A1 + (size_t)row*200 + (kg-256));
        } else {
          v = *(const float4*)(A0 + (size_t)row*K + kg);
        }
      }
      if constexpr (AFFINE){
        float4 scv = *(const float4*)(scale + kg);
        float4 shv = *(const float4*)(shift + kg);
        v.x = fmaf(v.x, scv.x, shv.x);
        v.y = fmaf(v.y, scv.y, shv.y);
        v.z = fmaf(v.z, scv.z, shv.z);
        v.w = fmaf(v.w, scv.w, shv.w);
      }
      As[(k4+0)*69 + rr] = v.x;
      As[(k4+1)*69 + rr] = v.y;
      As[(k4+2)*69 + rr] = v.z;
      As[(k4+3)*69 + rr] = v.w;
    }
    #pragma unroll
    for (int j = 0; j < 2; j++){
      int fid = tid + j*256;
      int kk = fid >> 4; int c4 = (fid & 15) << 2;
      int kg = kc0 + kk;
      float4 v = {0.f,0.f,0.f,0.f};
      if (kg < K) v = *(const float4*)(W + (size_t)kg*NWTOT + n0 + c4);
      *(float4*)(Bs + kk*64 + c4) = v;
    }
    __syncthreads();
    #pragma unroll
    for (int kk = 0; kk < 32; kk++){
      float4 b = *(const float4*)(Bs + kk*64 + tcol*4);
      float a0 = As[kk*69 + trow*2];
      float a1 = As[kk*69 + trow*2 + 1];
      acc[0][0] = fmaf(a0, b.x, acc[0][0]);
      acc[0][1] = fmaf(a0, b.y, acc[0][1]);
      acc[0][2] = fmaf(a0, b.z, acc[0][2]);
      acc[0][3] = fmaf(a0, b.w, acc[0][3]);
      acc[1][0] = fmaf(a1, b.x, acc[1][0]);
      acc[1][1] = fmaf(a1, b.y, acc[1][1]);
      acc[1][2] = fmaf(a1, b.z, acc[1][2]);
      acc[1][3] = fmaf(a1, b.w, acc[1][3]);
    }
    __syncthreads();
  }
  if (tid < 64){ s_sum[tid] = 0.f; s_sq[tid] = 0.f; }
  __syncthreads();
  float4 bv = *(const float4*)(bias + n0 + tcol*4);
  float psum[4] = {0,0,0,0}, psq[4] = {0,0,0,0};
  #pragma unroll
  for (int r = 0; r < 2; r++){
    int row = m0 + trow*2 + r;
    if (row < nrows){
      float4 o;
      o.x = fmaxf(acc[r][0] + bv.x, 0.f);
      o.y = fmaxf(acc[r][1] + bv.y, 0.f);
      o.z = fmaxf(acc[r][2] + bv.z, 0.f);
      o.w = fmaxf(acc[r][3] + bv.w, 0.f);
      *(float4*)(out + (size_t)row*NWTOT + n0 + tcol*4) = o;
      psum[0] += o.x; psq[0] += o.x*o.x;
      psum[1] += o.y; psq[1] += o.y*o.y;
      psum[2] += o.z; psq[2] += o.z*o.z;
      psum[3] += o.w; psq[3] += o.w*o.w;
    }
  }
  #pragma unroll
  for (int c = 0; c < 4; c++){
    psum[c] += __shfl_xor(psum[c], 16); psum[c] += __shfl_xor(psum[c], 32);
    psq[c]  += __shfl_xor(psq[c], 16);  psq[c]  += __shfl_xor(psq[c], 32);
  }
  if ((tid & 48) == 0){
    int f0 = tcol*4;
    atomicAdd(&s_sum[f0+0], psum[0]); atomicAdd(&s_sq[f0+0], psq[0]);
    atomicAdd(&s_sum[f0+1], psum[1]); atomicAdd(&s_sq[f0+1], psq[1]);
    atomicAdd(&s_sum[f0+2], psum[2]); atomicAdd(&s_sq[f0+2], psq[2]);
    atomicAdd(&s_sum[f0+3], psum[3]); atomicAdd(&s_sq[f0+3], psq[3]);
  }
  __syncthreads();
  float* gs = gstats + (size_t)(blockIdx.x & (NSLICE-1))*(2*NWTOT);
  if (tid < 64){
    atomicAdd(&gs[n0 + tid], s_sum[tid]);
    atomicAdd(&gs[NWTOT + n0 + tid], s_sq[tid]);
  }
}

// ---------------- final ----------------
__global__ __launch_bounds__(256) void k_final(
    const float* __restrict__ a2, const float* __restrict__ sc, const float* __restrict__ sh,
    const float* __restrict__ w, const float* __restrict__ b, float* __restrict__ out, int G)
{
  int gid  = blockIdx.x*blockDim.x + threadIdx.x;
  int wid  = gid >> 6;
  int lane = gid & 63;
  if (wid >= G) return;
  float2 v = ((const float2*)(a2 + (size_t)wid*128))[lane];
  int k = lane*2;
  float s = fmaf(v.x, sc[k], sh[k]) * w[k] + fmaf(v.y, sc[k+1], sh[k+1]) * w[k+1];
  #pragma unroll
  for (int o = 32; o > 0; o >>= 1) s += __shfl_down(s, o, 64);
  if (lane == 0) out[wid] = s + b[0];
}

// ---------------- launcher ----------------
extern "C" void kernel_launch(void* const* d_in, const int* in_sizes, int n_in,
                              void* d_out, int out_size, void* d_ws, size_t ws_size,
                              hipStream_t stream)
{
  (void)n_in; (void)out_size; (void)ws_size;
  const float* x    = (const float*)d_in[0];
  const int*   ei   = (const int*)d_in[1];
  const int*   batch= (const int*)d_in[2];
  const float* rdk  = (const float*)d_in[3];
  const float* W1   = (const float*)d_in[4];
  const float* b1   = (const float*)d_in[5];
  const float* g1   = (const float*)d_in[6];
  const float* be1  = (const float*)d_in[7];
  const float* W2   = (const float*)d_in[8];
  const float* b2   = (const float*)d_in[9];
  const float* g2   = (const float*)d_in[10];
  const float* be2  = (const float*)d_in[11];
  const float* mW1  = (const float*)d_in[12];
  const float* mb1  = (const float*)d_in[13];
  const float* mg1  = (const float*)d_in[14];
  const float* mbe1 = (const float*)d_in[15];
  const float* mW2  = (const float*)d_in[16];
  const float* mb2  = (const float*)d_in[17];
  const float* mg2  = (const float*)d_in[18];
  const float* mbe2 = (const float*)d_in[19];
  const float* mW3  = (const float*)d_in[20];
  const float* mb3  = (const float*)d_in[21];

  const int N = in_sizes[0] / 64;
  const int E = in_sizes[1] / 2;
  const int G = in_sizes[3] / 200;
  const int* erow = ei;
  const int* ecol = ei + E;
  const int nb = (N + BK_SIZE - 1) >> BK_BITS;

  size_t off = 0;
  auto alloc = [&](size_t bytes)->char*{
    char* p = (char*)d_ws + off;
    off += (bytes + 255) & ~(size_t)255;
    return p;
  };
  int*   offs   = (int*)  alloc(((size_t)N+1)*4);
  int*   csr    = (int*)  alloc((size_t)E*4);
  uint32_t* ebuf= (uint32_t*)alloc((size_t)NBK_MAX*EB_CAP*4);
  int*   bcur   = (int*)  alloc(NBK_MAX*4);
  float* dinv   = (float*)alloc((size_t)N*4);
  float* dsum   = (float*)alloc((size_t)N*4);
  uint16_t* xs  = (uint16_t*)alloc((size_t)N*64*2);
  uint16_t* z1  = (uint16_t*)alloc(((size_t)N+16)*64*2);
  uint8_t*  u   = (uint8_t*)alloc((size_t)N*128);
  uint16_t* z2  = (uint16_t*)alloc(((size_t)N+16)*128*2);
  uint16_t* WT1 = (uint16_t*)alloc((size_t)128*64*2);
  uint16_t* WT2 = (uint16_t*)alloc((size_t)256*128*2);
  float* embsum = (float*)alloc((size_t)G*256*4);
  int*   gstart = (int*)  alloc(((size_t)G+1)*4);
  float* a1     = (float*)alloc((size_t)G*256*4);
  float* a2     = (float*)alloc((size_t)G*128*4);
  float* gstats = (float*)alloc((size_t)4*NSLICE*2*256*4);
  float* scsh   = (float*)alloc((size_t)4*2*256*4);

  float* gs0 = gstats;
  float* gs1 = gstats + NSLICE*2*256;
  float* gs2 = gstats + 2*NSLICE*2*256;
  float* gs3 = gstats + 3*NSLICE*2*256;
  float* sc1 = scsh;        float* sh1 = scsh + 256;
  float* sc2 = scsh + 512;  float* sh2 = scsh + 768;
  float* sc3 = scsh + 1024; float* sh3 = scsh + 1280;
  float* sc4 = scsh + 1536; float* sh4 = scsh + 1792;

  int cbN   = (N + 255) / 256;
  int mblk  = (N + 63) / 64;
  int gblk32= (G + 31) / 32;
  int ablk  = (E + PA_TILE - 1) / PA_TILE;

  k_misc<<<1280 + cbN + 1 + 32 + 128, 256, 0, stream>>>(
      batch, gstart, N, G, cbN, W1, WT1, W2, WT2, bcur,
      (float4*)gstats, (float4*)embsum);

  k_passA<<<ablk,256,0,stream>>>(erow, ecol, bcur, ebuf, E);
  k_passB2<<<nb,256,0,stream>>>(ebuf, bcur, offs, dinv, csr, (const float4*)x, (ushort4*)xs, N, E, nb);

  k_agg1<<<(N+15)/16,256,0,stream>>>((const uint4*)xs, offs, csr, dinv, (uint4*)z1, dsum, N);
  k_gemm_mfma<64,128,128,false><<<dim3(mblk,1),256,0,stream>>>(z1, WT1, b1, nullptr, dinv, u, nullptr, gs0, N);
  k_bnfin<<<128,128,0,stream>>>(gs0, 128, 1.0f/(float)N, g1, be1, sc1, sh1);

  k_agg2<<<(N+15)/16,256,0,stream>>>((const uint4*)u, offs, csr, dinv, dsum, sc1, sh1, (uint4*)z2, N);
  k_gemm_mfma<128,256,128,true><<<dim3(mblk,2),256,0,stream>>>(z2, WT2, b2, batch, nullptr, nullptr, embsum, gs1, N);
  k_bnfin<<<256,128,0,stream>>>(gs1, 256, 1.0f/(float)N, g2, be2, sc2, sh2);

  k_gemm_mlp<456,256,true,false,true><<<dim3(gblk32,4),256,0,stream>>>(embsum, rdk, mW1, nullptr, nullptr, gstart, sc2, sh2, mb1, a1, gs2, G);
  k_bnfin<<<256,128,0,stream>>>(gs2, 256, 1.0f/(float)G, mg1, mbe1, sc3, sh3);
  k_gemm_mlp<256,128,false,true,false><<<dim3(gblk32,2),256,0,stream>>>(a1, nullptr, mW2, sc3, sh3, nullptr, nullptr, nullptr, mb2, a2, gs3, G);
  k_bnfin<<<128,128,0,stream>>>(gs3, 128, 1.0f/(float)G, mg2, mbe2, sc4, sh4);
  k_final<<<(G+3)/4,256,0,stream>>>(a2, sc4, sh4, mW3, mb3, (float*)d_out, G);
}